// Round 8
// baseline (620.475 us; speedup 1.0000x reference)
//
#include <hip/hip_runtime.h>
#include <math.h>

#define N_NODES 50000
#define N_EDGES 500000
#define D 128
#define CAT 384

typedef __bf16 v8bf __attribute__((ext_vector_type(8)));
typedef __bf16 v2bf __attribute__((ext_vector_type(2)));
typedef float v4f __attribute__((ext_vector_type(4)));

__device__ __forceinline__ float gelu_exact(float x) {
    return 0.5f * x * (1.0f + erff(x * 0.70710678118654752440f));
}

__device__ __forceinline__ v8bf cvt8(const float* __restrict__ p) {
    float4 f0 = *(const float4*)p;
    float4 f1 = *(const float4*)(p + 4);
    v8bf r;
    r[0] = (__bf16)f0.x; r[1] = (__bf16)f0.y; r[2] = (__bf16)f0.z; r[3] = (__bf16)f0.w;
    r[4] = (__bf16)f1.x; r[5] = (__bf16)f1.y; r[6] = (__bf16)f1.z; r[7] = (__bf16)f1.w;
    return r;
}

// ---------------------------------------------------------------------------
// One-shot bf16 weight conversion (layouts = direct 16B B-fragments).
__global__ __launch_bounds__(256) void k_cvtw(const float* __restrict__ msgW,
                                              const float* __restrict__ W1,
                                              const float* __restrict__ W2,
                                              const float* __restrict__ wih,
                                              const float* __restrict__ whh,
                                              __bf16* __restrict__ WB) {
    int i = blockIdx.x * 256 + threadIdx.x;
    float v;
    if (i < 32768) {
        int j = i >> 7, k = i & 127;
        v = (j < 128) ? msgW[j * CAT + k] : msgW[(j - 128) * CAT + 128 + k];
    } else if (i < 65536) {
        int ii = i - 32768; int j = ii >> 7, k = ii & 127;
        v = (j < 128) ? W1[j * CAT + k] : W1[(j - 128) * CAT + 128 + k];
    } else if (i < 81920) {
        int ii = i - 65536; int j = ii >> 7, k = ii & 127;
        v = W1[j * CAT + 256 + k];
    } else if (i < 83968) {
        v = W2[i - 81920];
    } else if (i < 133120) {
        v = wih[i - 83968];
    } else {
        v = whh[i - 133120];
    }
    WB[i] = (__bf16)v;
}

// ---------------------------------------------------------------------------
__global__ void k_relpart(const float* __restrict__ rel_emb,
                          const float* __restrict__ msg_W,
                          const float* __restrict__ msg_b,
                          __bf16* __restrict__ RPB) {
    int r = blockIdx.x;
    int j = threadIdx.x;
    const float* er = rel_emb + r * D;
    const float* wr = msg_W + j * CAT + 2 * D;
    float acc = msg_b[j];
    #pragma unroll 8
    for (int k = 0; k < D; ++k) acc += er[k] * wr[k];
    RPB[r * D + j] = (__bf16)acc;
}

// ---------------------------------------------------------------------------
// MFMA node projection (fp32 input). Output-col remap: tile col c -> j =
// half*128 + 8c + jt, so each thread's 8 output elems are contiguous (v8bf store).
__global__ __launch_bounds__(256) void k_proj2_f32(const float* __restrict__ in,
                                                   const __bf16* __restrict__ wb,
                                                   __bf16* __restrict__ out) {
    int t = threadIdx.x;
    int lane = t & 63, wid = t >> 6;
    int g = lane >> 4, c = lane & 15;
    int nbase = blockIdx.x * 64 + wid * 16;

    int nrow = min(nbase + c, N_NODES - 1);
    const float* ir = in + (size_t)nrow * D + g * 8;
    v8bf afrag[4];
    #pragma unroll
    for (int kc = 0; kc < 4; ++kc) afrag[kc] = cvt8(ir + kc * 32);

    #pragma unroll
    for (int half = 0; half < 2; ++half) {
        v4f acc[8];
        #pragma unroll 2
        for (int jt = 0; jt < 8; ++jt) {
            const __bf16* wr = wb + (size_t)(half * 128 + 8 * c + jt) * 128 + g * 8;
            v4f a4 = (v4f){0.f, 0.f, 0.f, 0.f};
            #pragma unroll
            for (int kc = 0; kc < 4; ++kc)
                a4 = __builtin_amdgcn_mfma_f32_16x16x32_bf16(afrag[kc], *(const v8bf*)(wr + kc * 32), a4, 0, 0, 0);
            acc[jt] = a4;
        }
        #pragma unroll
        for (int r = 0; r < 4; ++r) {
            int node = nbase + g * 4 + r;
            v8bf o;
            #pragma unroll
            for (int jt = 0; jt < 8; ++jt) o[jt] = (__bf16)acc[jt][r];
            if (node < N_NODES)
                *(v8bf*)(out + (size_t)node * 256 + half * 128 + 8 * c) = o;
        }
    }
}

// bf16-input variant (for NFUB -> QSTB).
__global__ __launch_bounds__(256) void k_proj2_b16(const __bf16* __restrict__ in,
                                                   const __bf16* __restrict__ wb,
                                                   __bf16* __restrict__ out) {
    int t = threadIdx.x;
    int lane = t & 63, wid = t >> 6;
    int g = lane >> 4, c = lane & 15;
    int nbase = blockIdx.x * 64 + wid * 16;

    int nrow = min(nbase + c, N_NODES - 1);
    const __bf16* ir = in + (size_t)nrow * D + g * 8;
    v8bf afrag[4];
    #pragma unroll
    for (int kc = 0; kc < 4; ++kc) afrag[kc] = *(const v8bf*)(ir + kc * 32);

    #pragma unroll
    for (int half = 0; half < 2; ++half) {
        v4f acc[8];
        #pragma unroll 2
        for (int jt = 0; jt < 8; ++jt) {
            const __bf16* wr = wb + (size_t)(half * 128 + 8 * c + jt) * 128 + g * 8;
            v4f a4 = (v4f){0.f, 0.f, 0.f, 0.f};
            #pragma unroll
            for (int kc = 0; kc < 4; ++kc)
                a4 = __builtin_amdgcn_mfma_f32_16x16x32_bf16(afrag[kc], *(const v8bf*)(wr + kc * 32), a4, 0, 0, 0);
            acc[jt] = a4;
        }
        #pragma unroll
        for (int r = 0; r < 4; ++r) {
            int node = nbase + g * 4 + r;
            v8bf o;
            #pragma unroll
            for (int jt = 0; jt < 8; ++jt) o[jt] = (__bf16)acc[jt][r];
            if (node < N_NODES)
                *(v8bf*)(out + (size_t)node * 256 + half * 128 + 8 * c) = o;
        }
    }
}

// ---------------------------------------------------------------------------
// CSR build: histogram -> scan -> scatter.
__global__ __launch_bounds__(256) void k_hist(const int* __restrict__ ei,
                                              int* __restrict__ counts) {
    int e = blockIdx.x * 256 + threadIdx.x;
    if (e < N_EDGES) atomicAdd(&counts[ei[N_EDGES + e]], 1);
}

__global__ __launch_bounds__(256) void k_scan(const int* __restrict__ counts,
                                              int* __restrict__ offsets,
                                              int* __restrict__ cursor) {
    __shared__ int part[256];
    int t = threadIdx.x;
    const int CH = 196;
    int lo = t * CH, hi = min(lo + CH, N_NODES);
    int s = 0;
    for (int i = lo; i < hi; ++i) s += counts[i];
    part[t] = s;
    __syncthreads();
    for (int d = 1; d < 256; d <<= 1) {
        int v = (t >= d) ? part[t - d] : 0;
        __syncthreads();
        part[t] += v;
        __syncthreads();
    }
    int run = (t == 0) ? 0 : part[t - 1];
    for (int i = lo; i < hi; ++i) {
        offsets[i] = run;
        cursor[i] = run;
        run += counts[i];
    }
    if (t == 255) offsets[N_NODES] = run;
}

__global__ __launch_bounds__(256) void k_scatter(const int* __restrict__ ei,
                                                 int* __restrict__ cursor,
                                                 int* __restrict__ elist) {
    int e = blockIdx.x * 256 + threadIdx.x;
    if (e < N_EDGES) {
        int slot = atomicAdd(&cursor[ei[N_EDGES + e]], 1);
        elist[slot] = e;
    }
}

// ---------------------------------------------------------------------------
// Aggregation, atomic-free; one wave per node; index-prefetch pipeline;
// bf16 output (only consumer converts to bf16 anyway).
__global__ __launch_bounds__(256) void k_agg(const __bf16* __restrict__ PSTB,
                                             const __bf16* __restrict__ RPB,
                                             const int* __restrict__ ei,
                                             const int* __restrict__ lab,
                                             const int* __restrict__ offsets,
                                             const int* __restrict__ elist,
                                             __bf16* __restrict__ agg) {
    int t = threadIdx.x;
    int wid = t >> 6, lane = t & 63;
    int n = blockIdx.x * 4 + wid;
    if (n >= N_NODES) return;
    int beg = offsets[n], end = offsets[n + 1];

    v2bf ptv = *(const v2bf*)(PSTB + (size_t)n * 256 + 128 + lane * 2);
    float pt0 = (float)ptv[0], pt1 = (float)ptv[1];

    float a0 = 0.f, a1 = 0.f;
    int idx = beg;
    int s_nx = 0, l_nx = 0;
    if (idx < end) { int e = elist[idx]; s_nx = ei[e]; l_nx = lab[e]; }
    while (idx < end) {
        int s = s_nx, l = l_nx;
        v2bf ps = *(const v2bf*)(PSTB + (size_t)s * 256 + lane * 2);
        v2bf rp = *(const v2bf*)(RPB + (size_t)l * D + lane * 2);
        ++idx;
        if (idx < end) { int e = elist[idx]; s_nx = ei[e]; l_nx = lab[e]; }
        a0 += gelu_exact((float)ps[0] + pt0 + (float)rp[0]);
        a1 += gelu_exact((float)ps[1] + pt1 + (float)rp[1]);
    }
    v2bf o; o[0] = (__bf16)a0; o[1] = (__bf16)a1;
    *(v2bf*)(agg + (size_t)n * D + lane * 2) = o;
}

// ---------------------------------------------------------------------------
// MFMA GRU, output-col remap j = 8c + jt; bf16 agg input, bf16 nfu output.
__global__ __launch_bounds__(256) void k_gru_mfma(const __bf16* __restrict__ agg,
                                                  const float* __restrict__ nf,
                                                  const __bf16* __restrict__ WIH,
                                                  const __bf16* __restrict__ WHH,
                                                  const float* __restrict__ b_ih,
                                                  const float* __restrict__ b_hh,
                                                  __bf16* __restrict__ nfu) {
    int t = threadIdx.x;
    int lane = t & 63, wid = t >> 6;
    int g = lane >> 4, c = lane & 15;
    int nbase = blockIdx.x * 64 + wid * 16;

    int nrow = min(nbase + c, N_NODES - 1);
    const __bf16* ar = agg + (size_t)nrow * D + g * 8;
    const float* hr = nf + (size_t)nrow * D + g * 8;
    v8bf afrag[4], hfrag[4];
    #pragma unroll
    for (int kc = 0; kc < 4; ++kc) {
        afrag[kc] = *(const v8bf*)(ar + kc * 32);
        hfrag[kc] = cvt8(hr + kc * 32);
    }

    // preload h rows (cols 8c..8c+8) for the epilogue
    float h8[4][8];
    #pragma unroll
    for (int r = 0; r < 4; ++r) {
        int node = min(nbase + g * 4 + r, N_NODES - 1);
        float4 f0 = *(const float4*)(nf + (size_t)node * D + 8 * c);
        float4 f1 = *(const float4*)(nf + (size_t)node * D + 8 * c + 4);
        h8[r][0]=f0.x; h8[r][1]=f0.y; h8[r][2]=f0.z; h8[r][3]=f0.w;
        h8[r][4]=f1.x; h8[r][5]=f1.y; h8[r][6]=f1.z; h8[r][7]=f1.w;
    }

    v8bf o[4];
    for (int jt = 0; jt < 8; ++jt) {
        int j = 8 * c + jt;
        const __bf16* wir = WIH + (size_t)j * 128 + g * 8;
        const __bf16* whr = WHH + (size_t)j * 128 + g * 8;
        v4f a_ir = (v4f){0.f,0.f,0.f,0.f}, a_iz = a_ir, a_in = a_ir;
        v4f a_hr = a_ir, a_hz = a_ir, a_hn = a_ir;
        #pragma unroll
        for (int kc = 0; kc < 4; ++kc) {
            a_ir = __builtin_amdgcn_mfma_f32_16x16x32_bf16(afrag[kc], *(const v8bf*)(wir + kc * 32), a_ir, 0, 0, 0);
            a_iz = __builtin_amdgcn_mfma_f32_16x16x32_bf16(afrag[kc], *(const v8bf*)(wir + 128 * 128 + kc * 32), a_iz, 0, 0, 0);
            a_in = __builtin_amdgcn_mfma_f32_16x16x32_bf16(afrag[kc], *(const v8bf*)(wir + 256 * 128 + kc * 32), a_in, 0, 0, 0);
            a_hr = __builtin_amdgcn_mfma_f32_16x16x32_bf16(hfrag[kc], *(const v8bf*)(whr + kc * 32), a_hr, 0, 0, 0);
            a_hz = __builtin_amdgcn_mfma_f32_16x16x32_bf16(hfrag[kc], *(const v8bf*)(whr + 128 * 128 + kc * 32), a_hz, 0, 0, 0);
            a_hn = __builtin_amdgcn_mfma_f32_16x16x32_bf16(hfrag[kc], *(const v8bf*)(whr + 256 * 128 + kc * 32), a_hn, 0, 0, 0);
        }
        float bir = b_ih[j], biz = b_ih[128 + j], bin = b_ih[256 + j];
        float bhr = b_hh[j], bhz = b_hh[128 + j], bhn = b_hh[256 + j];
        #pragma unroll
        for (int r = 0; r < 4; ++r) {
            float irv = a_ir[r] + bir, hrv = a_hr[r] + bhr;
            float izv = a_iz[r] + biz, hzv = a_hz[r] + bhz;
            float inv = a_in[r] + bin, hnv = a_hn[r] + bhn;
            float rg = 1.f / (1.f + expf(-(irv + hrv)));
            float zg = 1.f / (1.f + expf(-(izv + hzv)));
            float ng = tanhf(inv + rg * hnv);
            o[r][jt] = (__bf16)((1.f - zg) * ng + zg * h8[r][jt]);
        }
    }
    #pragma unroll
    for (int r = 0; r < 4; ++r) {
        int node = nbase + g * 4 + r;
        if (node < N_NODES) *(v8bf*)(nfu + (size_t)node * D + 8 * c) = o[r];
    }
}

// ---------------------------------------------------------------------------
// MFMA classifier, output-col remap j = 8c + jt:
//  - QST gathers become 8x coalesced v8bf loads per thread (were 64 scalar)
//  - hc epilogue: one ds_write_b128 per row (chunk-XOR swizzled)
//  - GEMM2 reads conflict-free via the same chunk swizzle
__global__ __launch_bounds__(256) void k_cls_mfma(const float* __restrict__ ef,
                                                  const __bf16* __restrict__ QSTB,
                                                  const __bf16* __restrict__ V3,
                                                  const float* __restrict__ b1,
                                                  const __bf16* __restrict__ W2B,
                                                  const float* __restrict__ b2,
                                                  const int* __restrict__ ei,
                                                  float* __restrict__ out) {
    __shared__ __align__(16) __bf16 hc_s[64][128];
    __shared__ __align__(16) __bf16 w2_s[16][128];
    int t = threadIdx.x;
    int lane = t & 63, w = t >> 6;
    int g = lane >> 4, c = lane & 15;
    int e0 = blockIdx.x * 64;
    int e_base = e0 + w * 16;

    // stage W2 chunk-swizzled: 256 threads x one 16B chunk
    {
        int r = t >> 4, ch = t & 15;
        v8bf v = *(const v8bf*)(W2B + r * 128 + ch * 8);
        *(v8bf*)&w2_s[r][8 * (ch ^ (r & 7))] = v;
    }

    // edge indices (uniform within 16-lane group)
    int sr[4], tr[4];
    #pragma unroll
    for (int r = 0; r < 4; ++r) {
        int e = min(e_base + g * 4 + r, N_EDGES - 1);
        sr[r] = ei[e];
        tr[r] = ei[N_EDGES + e];
    }
    // vector QST gathers: cols [8c,8c+8) of src half / tgt half
    v8bf qsv[4], qtv[4];
    #pragma unroll
    for (int r = 0; r < 4; ++r) {
        qsv[r] = *(const v8bf*)(QSTB + (size_t)sr[r] * 256 + 8 * c);
        qtv[r] = *(const v8bf*)(QSTB + (size_t)tr[r] * 256 + 128 + 8 * c);
    }
    float4 b1a = *(const float4*)(b1 + 8 * c);
    float4 b1b = *(const float4*)(b1 + 8 * c + 4);
    float b1r[8] = {b1a.x, b1a.y, b1a.z, b1a.w, b1b.x, b1b.y, b1b.z, b1b.w};

    // A fragments from ef
    int er = min(e_base + c, N_EDGES - 1);
    const float* efr = ef + (size_t)er * D + g * 8;
    v8bf afrag[4];
    #pragma unroll
    for (int kc = 0; kc < 4; ++kc) afrag[kc] = cvt8(efr + kc * 32);

    // GEMM1: B row = 8c + jt
    v4f acc[8];
    #pragma unroll 2
    for (int jt = 0; jt < 8; ++jt) {
        const __bf16* wr = V3 + (size_t)(8 * c + jt) * 128 + g * 8;
        v4f a4 = (v4f){0.f, 0.f, 0.f, 0.f};
        #pragma unroll
        for (int kc = 0; kc < 4; ++kc)
            a4 = __builtin_amdgcn_mfma_f32_16x16x32_bf16(afrag[kc], *(const v8bf*)(wr + kc * 32), a4, 0, 0, 0);
        acc[jt] = a4;
    }

    // epilogue: fused gather-add + gelu -> one v8bf LDS store per row
    #pragma unroll
    for (int r = 0; r < 4; ++r) {
        int el = w * 16 + g * 4 + r;
        v8bf o;
        #pragma unroll
        for (int jt = 0; jt < 8; ++jt) {
            float v = acc[jt][r] + (float)qsv[r][jt] + (float)qtv[r][jt] + b1r[jt];
            o[jt] = (__bf16)gelu_exact(v);
        }
        *(v8bf*)&hc_s[el][8 * (c ^ (el & 7))] = o;
    }
    __syncthreads();

    // GEMM2: A = hc rows, B = W2 (both chunk-swizzled)
    v4f acc2 = (v4f){0.f, 0.f, 0.f, 0.f};
    int arow = w * 16 + c;
    #pragma unroll
    for (int kc = 0; kc < 4; ++kc) {
        int ch = g + 4 * kc;
        v8bf aa = *(const v8bf*)&hc_s[arow][8 * (ch ^ (c & 7))];
        v8bf bb = *(const v8bf*)&w2_s[c][8 * (ch ^ (c & 7))];
        acc2 = __builtin_amdgcn_mfma_f32_16x16x32_bf16(aa, bb, acc2, 0, 0, 0);
    }
    float b2c = b2[c];
    #pragma unroll
    for (int r = 0; r < 4; ++r) {
        int e = e_base + g * 4 + r;
        if (e < N_EDGES) out[(size_t)e * 16 + c] = acc2[r] + b2c;
    }
}

// ---------------------------------------------------------------------------
extern "C" void kernel_launch(void* const* d_in, const int* in_sizes, int n_in,
                              void* d_out, int out_size, void* d_ws, size_t ws_size,
                              hipStream_t stream) {
    const float* nf   = (const float*)d_in[0];
    const float* ef   = (const float*)d_in[1];
    const int*   ei   = (const int*)d_in[2];
    const int*   lab  = (const int*)d_in[3];
    const float* rel  = (const float*)d_in[4];
    const float* msgW = (const float*)d_in[5];
    const float* msgb = (const float*)d_in[6];
    const float* wih  = (const float*)d_in[7];
    const float* whh  = (const float*)d_in[8];
    const float* bih  = (const float*)d_in[9];
    const float* bhh  = (const float*)d_in[10];
    const float* W1   = (const float*)d_in[11];
    const float* b1   = (const float*)d_in[12];
    const float* W2   = (const float*)d_in[13];
    const float* b2   = (const float*)d_in[14];
    float* out = (float*)d_out;

    char* ws = (char*)d_ws;
    __bf16* WB      = (__bf16*)(ws);                  // 364.5 KB
    __bf16* RPB     = (__bf16*)(ws + 524288);         // 16 KB
    int*    offsets = (int*)(ws + 1048576);           // 200 KB (N+1)
    int*    counts  = (int*)(ws + 1310720);           // 200 KB
    int*    cursor  = (int*)(ws + 1572864);           // 200 KB
    int*    elist   = (int*)(ws + 1835008);           // 2 MB
    __bf16* PSTB    = (__bf16*)(ws + 4194304);        // 25.6 MB
    __bf16* AGG     = (__bf16*)(ws + 33554432);       // 12.8 MB
    __bf16* NFUB    = (__bf16*)(ws + 50331648);       // 12.8 MB
    __bf16* QSTB    = PSTB;                           // reuse after k_agg

    __bf16* WP1 = WB;
    __bf16* WQ1 = WB + 32768;
    __bf16* V3  = WB + 65536;
    __bf16* W2B = WB + 81920;
    __bf16* WIH = WB + 83968;
    __bf16* WHH = WB + 133120;

    int nblk = (N_NODES + 63) / 64;
    int eblk = (N_EDGES + 255) / 256;

    k_cvtw<<<712, 256, 0, stream>>>(msgW, W1, W2, wih, whh, WB);
    k_relpart<<<64, 128, 0, stream>>>(rel, msgW, msgb, RPB);
    hipMemsetAsync(counts, 0, N_NODES * sizeof(int), stream);
    k_hist<<<eblk, 256, 0, stream>>>(ei, counts);
    k_proj2_f32<<<nblk, 256, 0, stream>>>(nf, WP1, PSTB);
    k_scan<<<1, 256, 0, stream>>>(counts, offsets, cursor);
    k_scatter<<<eblk, 256, 0, stream>>>(ei, cursor, elist);
    k_agg<<<(N_NODES + 3) / 4, 256, 0, stream>>>(PSTB, RPB, ei, lab, offsets, elist, AGG);
    k_gru_mfma<<<nblk, 256, 0, stream>>>(AGG, nf, WIH, WHH, bih, bhh, NFUB);
    k_proj2_b16<<<nblk, 256, 0, stream>>>(NFUB, WQ1, QSTB);
    k_cls_mfma<<<(N_EDGES + 63) / 64, 256, 0, stream>>>(ef, QSTB, V3, b1, W2B, b2, ei, out);
}

// Round 9
// 619.280 us; speedup vs baseline: 1.0019x; 1.0019x over previous
//
#include <hip/hip_runtime.h>
#include <math.h>

#define N_NODES 50000
#define N_EDGES 500000
#define D 128
#define CAT 384

typedef __bf16 v8bf __attribute__((ext_vector_type(8)));
typedef __bf16 v2bf __attribute__((ext_vector_type(2)));
typedef float v4f __attribute__((ext_vector_type(4)));

__device__ __forceinline__ float gelu_exact(float x) {
    return 0.5f * x * (1.0f + erff(x * 0.70710678118654752440f));
}

__device__ __forceinline__ v8bf cvt8(const float* __restrict__ p) {
    float4 f0 = *(const float4*)p;
    float4 f1 = *(const float4*)(p + 4);
    v8bf r;
    r[0] = (__bf16)f0.x; r[1] = (__bf16)f0.y; r[2] = (__bf16)f0.z; r[3] = (__bf16)f0.w;
    r[4] = (__bf16)f1.x; r[5] = (__bf16)f1.y; r[6] = (__bf16)f1.z; r[7] = (__bf16)f1.w;
    return r;
}

// ---------------------------------------------------------------------------
// One-shot bf16 weight conversion (layouts = direct 16B B-fragments).
__global__ __launch_bounds__(256) void k_cvtw(const float* __restrict__ msgW,
                                              const float* __restrict__ W1,
                                              const float* __restrict__ W2,
                                              const float* __restrict__ wih,
                                              const float* __restrict__ whh,
                                              __bf16* __restrict__ WB) {
    int i = blockIdx.x * 256 + threadIdx.x;
    float v;
    if (i < 32768) {
        int j = i >> 7, k = i & 127;
        v = (j < 128) ? msgW[j * CAT + k] : msgW[(j - 128) * CAT + 128 + k];
    } else if (i < 65536) {
        int ii = i - 32768; int j = ii >> 7, k = ii & 127;
        v = (j < 128) ? W1[j * CAT + k] : W1[(j - 128) * CAT + 128 + k];
    } else if (i < 81920) {
        int ii = i - 65536; int j = ii >> 7, k = ii & 127;
        v = W1[j * CAT + 256 + k];
    } else if (i < 83968) {
        v = W2[i - 81920];
    } else if (i < 133120) {
        v = wih[i - 83968];
    } else {
        v = whh[i - 133120];
    }
    WB[i] = (__bf16)v;
}

// ---------------------------------------------------------------------------
__global__ void k_relpart(const float* __restrict__ rel_emb,
                          const float* __restrict__ msg_W,
                          const float* __restrict__ msg_b,
                          __bf16* __restrict__ RPB) {
    int r = blockIdx.x;
    int j = threadIdx.x;
    const float* er = rel_emb + r * D;
    const float* wr = msg_W + j * CAT + 2 * D;
    float acc = msg_b[j];
    #pragma unroll 8
    for (int k = 0; k < D; ++k) acc += er[k] * wr[k];
    RPB[r * D + j] = (__bf16)acc;
}

// ---------------------------------------------------------------------------
// MFMA node projection (fp32 input). Output-col remap: tile col c -> j =
// half*128 + 8c + jt, so each thread's 8 output elems are contiguous (v8bf store).
__global__ __launch_bounds__(256) void k_proj2_f32(const float* __restrict__ in,
                                                   const __bf16* __restrict__ wb,
                                                   __bf16* __restrict__ out) {
    int t = threadIdx.x;
    int lane = t & 63, wid = t >> 6;
    int g = lane >> 4, c = lane & 15;
    int nbase = blockIdx.x * 64 + wid * 16;

    int nrow = min(nbase + c, N_NODES - 1);
    const float* ir = in + (size_t)nrow * D + g * 8;
    v8bf afrag[4];
    #pragma unroll
    for (int kc = 0; kc < 4; ++kc) afrag[kc] = cvt8(ir + kc * 32);

    #pragma unroll
    for (int half = 0; half < 2; ++half) {
        v4f acc[8];
        #pragma unroll 2
        for (int jt = 0; jt < 8; ++jt) {
            const __bf16* wr = wb + (size_t)(half * 128 + 8 * c + jt) * 128 + g * 8;
            v4f a4 = (v4f){0.f, 0.f, 0.f, 0.f};
            #pragma unroll
            for (int kc = 0; kc < 4; ++kc)
                a4 = __builtin_amdgcn_mfma_f32_16x16x32_bf16(afrag[kc], *(const v8bf*)(wr + kc * 32), a4, 0, 0, 0);
            acc[jt] = a4;
        }
        #pragma unroll
        for (int r = 0; r < 4; ++r) {
            int node = nbase + g * 4 + r;
            v8bf o;
            #pragma unroll
            for (int jt = 0; jt < 8; ++jt) o[jt] = (__bf16)acc[jt][r];
            if (node < N_NODES)
                *(v8bf*)(out + (size_t)node * 256 + half * 128 + 8 * c) = o;
        }
    }
}

// bf16-input variant (for NFUB -> QSTB).
__global__ __launch_bounds__(256) void k_proj2_b16(const __bf16* __restrict__ in,
                                                   const __bf16* __restrict__ wb,
                                                   __bf16* __restrict__ out) {
    int t = threadIdx.x;
    int lane = t & 63, wid = t >> 6;
    int g = lane >> 4, c = lane & 15;
    int nbase = blockIdx.x * 64 + wid * 16;

    int nrow = min(nbase + c, N_NODES - 1);
    const __bf16* ir = in + (size_t)nrow * D + g * 8;
    v8bf afrag[4];
    #pragma unroll
    for (int kc = 0; kc < 4; ++kc) afrag[kc] = *(const v8bf*)(ir + kc * 32);

    #pragma unroll
    for (int half = 0; half < 2; ++half) {
        v4f acc[8];
        #pragma unroll 2
        for (int jt = 0; jt < 8; ++jt) {
            const __bf16* wr = wb + (size_t)(half * 128 + 8 * c + jt) * 128 + g * 8;
            v4f a4 = (v4f){0.f, 0.f, 0.f, 0.f};
            #pragma unroll
            for (int kc = 0; kc < 4; ++kc)
                a4 = __builtin_amdgcn_mfma_f32_16x16x32_bf16(afrag[kc], *(const v8bf*)(wr + kc * 32), a4, 0, 0, 0);
            acc[jt] = a4;
        }
        #pragma unroll
        for (int r = 0; r < 4; ++r) {
            int node = nbase + g * 4 + r;
            v8bf o;
            #pragma unroll
            for (int jt = 0; jt < 8; ++jt) o[jt] = (__bf16)acc[jt][r];
            if (node < N_NODES)
                *(v8bf*)(out + (size_t)node * 256 + half * 128 + 8 * c) = o;
        }
    }
}

// ---------------------------------------------------------------------------
// CSR build: histogram -> scan -> scatter.
__global__ __launch_bounds__(256) void k_hist(const int* __restrict__ ei,
                                              int* __restrict__ counts) {
    int e = blockIdx.x * 256 + threadIdx.x;
    if (e < N_EDGES) atomicAdd(&counts[ei[N_EDGES + e]], 1);
}

__global__ __launch_bounds__(256) void k_scan(const int* __restrict__ counts,
                                              int* __restrict__ offsets,
                                              int* __restrict__ cursor) {
    __shared__ int part[256];
    int t = threadIdx.x;
    const int CH = 196;
    int lo = t * CH, hi = min(lo + CH, N_NODES);
    int s = 0;
    for (int i = lo; i < hi; ++i) s += counts[i];
    part[t] = s;
    __syncthreads();
    for (int d = 1; d < 256; d <<= 1) {
        int v = (t >= d) ? part[t - d] : 0;
        __syncthreads();
        part[t] += v;
        __syncthreads();
    }
    int run = (t == 0) ? 0 : part[t - 1];
    for (int i = lo; i < hi; ++i) {
        offsets[i] = run;
        cursor[i] = run;
        run += counts[i];
    }
    if (t == 255) offsets[N_NODES] = run;
}

__global__ __launch_bounds__(256) void k_scatter(const int* __restrict__ ei,
                                                 int* __restrict__ cursor,
                                                 int* __restrict__ elist) {
    int e = blockIdx.x * 256 + threadIdx.x;
    if (e < N_EDGES) {
        int slot = atomicAdd(&cursor[ei[N_EDGES + e]], 1);
        elist[slot] = e;
    }
}

// ---------------------------------------------------------------------------
// Aggregation, atomic-free; one wave per node; index-prefetch pipeline;
// bf16 output (only consumer converts to bf16 anyway).
__global__ __launch_bounds__(256) void k_agg(const __bf16* __restrict__ PSTB,
                                             const __bf16* __restrict__ RPB,
                                             const int* __restrict__ ei,
                                             const int* __restrict__ lab,
                                             const int* __restrict__ offsets,
                                             const int* __restrict__ elist,
                                             __bf16* __restrict__ agg) {
    int t = threadIdx.x;
    int wid = t >> 6, lane = t & 63;
    int n = blockIdx.x * 4 + wid;
    if (n >= N_NODES) return;
    int beg = offsets[n], end = offsets[n + 1];

    v2bf ptv = *(const v2bf*)(PSTB + (size_t)n * 256 + 128 + lane * 2);
    float pt0 = (float)ptv[0], pt1 = (float)ptv[1];

    float a0 = 0.f, a1 = 0.f;
    int idx = beg;
    int s_nx = 0, l_nx = 0;
    if (idx < end) { int e = elist[idx]; s_nx = ei[e]; l_nx = lab[e]; }
    while (idx < end) {
        int s = s_nx, l = l_nx;
        v2bf ps = *(const v2bf*)(PSTB + (size_t)s * 256 + lane * 2);
        v2bf rp = *(const v2bf*)(RPB + (size_t)l * D + lane * 2);
        ++idx;
        if (idx < end) { int e = elist[idx]; s_nx = ei[e]; l_nx = lab[e]; }
        a0 += gelu_exact((float)ps[0] + pt0 + (float)rp[0]);
        a1 += gelu_exact((float)ps[1] + pt1 + (float)rp[1]);
    }
    v2bf o; o[0] = (__bf16)a0; o[1] = (__bf16)a1;
    *(v2bf*)(agg + (size_t)n * D + lane * 2) = o;
}

// ---------------------------------------------------------------------------
// MFMA GRU, output-col remap j = 8c + jt; bf16 agg input, bf16 nfu output.
__global__ __launch_bounds__(256) void k_gru_mfma(const __bf16* __restrict__ agg,
                                                  const float* __restrict__ nf,
                                                  const __bf16* __restrict__ WIH,
                                                  const __bf16* __restrict__ WHH,
                                                  const float* __restrict__ b_ih,
                                                  const float* __restrict__ b_hh,
                                                  __bf16* __restrict__ nfu) {
    int t = threadIdx.x;
    int lane = t & 63, wid = t >> 6;
    int g = lane >> 4, c = lane & 15;
    int nbase = blockIdx.x * 64 + wid * 16;

    int nrow = min(nbase + c, N_NODES - 1);
    const __bf16* ar = agg + (size_t)nrow * D + g * 8;
    const float* hr = nf + (size_t)nrow * D + g * 8;
    v8bf afrag[4], hfrag[4];
    #pragma unroll
    for (int kc = 0; kc < 4; ++kc) {
        afrag[kc] = *(const v8bf*)(ar + kc * 32);
        hfrag[kc] = cvt8(hr + kc * 32);
    }

    // preload h rows (cols 8c..8c+8) for the epilogue
    float h8[4][8];
    #pragma unroll
    for (int r = 0; r < 4; ++r) {
        int node = min(nbase + g * 4 + r, N_NODES - 1);
        float4 f0 = *(const float4*)(nf + (size_t)node * D + 8 * c);
        float4 f1 = *(const float4*)(nf + (size_t)node * D + 8 * c + 4);
        h8[r][0]=f0.x; h8[r][1]=f0.y; h8[r][2]=f0.z; h8[r][3]=f0.w;
        h8[r][4]=f1.x; h8[r][5]=f1.y; h8[r][6]=f1.z; h8[r][7]=f1.w;
    }

    v8bf o[4];
    for (int jt = 0; jt < 8; ++jt) {
        int j = 8 * c + jt;
        const __bf16* wir = WIH + (size_t)j * 128 + g * 8;
        const __bf16* whr = WHH + (size_t)j * 128 + g * 8;
        v4f a_ir = (v4f){0.f,0.f,0.f,0.f}, a_iz = a_ir, a_in = a_ir;
        v4f a_hr = a_ir, a_hz = a_ir, a_hn = a_ir;
        #pragma unroll
        for (int kc = 0; kc < 4; ++kc) {
            a_ir = __builtin_amdgcn_mfma_f32_16x16x32_bf16(afrag[kc], *(const v8bf*)(wir + kc * 32), a_ir, 0, 0, 0);
            a_iz = __builtin_amdgcn_mfma_f32_16x16x32_bf16(afrag[kc], *(const v8bf*)(wir + 128 * 128 + kc * 32), a_iz, 0, 0, 0);
            a_in = __builtin_amdgcn_mfma_f32_16x16x32_bf16(afrag[kc], *(const v8bf*)(wir + 256 * 128 + kc * 32), a_in, 0, 0, 0);
            a_hr = __builtin_amdgcn_mfma_f32_16x16x32_bf16(hfrag[kc], *(const v8bf*)(whr + kc * 32), a_hr, 0, 0, 0);
            a_hz = __builtin_amdgcn_mfma_f32_16x16x32_bf16(hfrag[kc], *(const v8bf*)(whr + 128 * 128 + kc * 32), a_hz, 0, 0, 0);
            a_hn = __builtin_amdgcn_mfma_f32_16x16x32_bf16(hfrag[kc], *(const v8bf*)(whr + 256 * 128 + kc * 32), a_hn, 0, 0, 0);
        }
        float bir = b_ih[j], biz = b_ih[128 + j], bin = b_ih[256 + j];
        float bhr = b_hh[j], bhz = b_hh[128 + j], bhn = b_hh[256 + j];
        #pragma unroll
        for (int r = 0; r < 4; ++r) {
            float irv = a_ir[r] + bir, hrv = a_hr[r] + bhr;
            float izv = a_iz[r] + biz, hzv = a_hz[r] + bhz;
            float inv = a_in[r] + bin, hnv = a_hn[r] + bhn;
            float rg = 1.f / (1.f + expf(-(irv + hrv)));
            float zg = 1.f / (1.f + expf(-(izv + hzv)));
            float ng = tanhf(inv + rg * hnv);
            o[r][jt] = (__bf16)((1.f - zg) * ng + zg * h8[r][jt]);
        }
    }
    #pragma unroll
    for (int r = 0; r < 4; ++r) {
        int node = nbase + g * 4 + r;
        if (node < N_NODES) *(v8bf*)(nfu + (size_t)node * D + 8 * c) = o[r];
    }
}

// ---------------------------------------------------------------------------
// MFMA classifier, output-col remap j = 8c + jt:
//  - QST gathers become 8x coalesced v8bf loads per thread (were 64 scalar)
//  - hc epilogue: one ds_write_b128 per row (chunk-XOR swizzled)
//  - GEMM2 reads conflict-free via the same chunk swizzle
__global__ __launch_bounds__(256) void k_cls_mfma(const float* __restrict__ ef,
                                                  const __bf16* __restrict__ QSTB,
                                                  const __bf16* __restrict__ V3,
                                                  const float* __restrict__ b1,
                                                  const __bf16* __restrict__ W2B,
                                                  const float* __restrict__ b2,
                                                  const int* __restrict__ ei,
                                                  float* __restrict__ out) {
    __shared__ __align__(16) __bf16 hc_s[64][128];
    __shared__ __align__(16) __bf16 w2_s[16][128];
    int t = threadIdx.x;
    int lane = t & 63, w = t >> 6;
    int g = lane >> 4, c = lane & 15;
    int e0 = blockIdx.x * 64;
    int e_base = e0 + w * 16;

    // stage W2 chunk-swizzled: 256 threads x one 16B chunk
    {
        int r = t >> 4, ch = t & 15;
        v8bf v = *(const v8bf*)(W2B + r * 128 + ch * 8);
        *(v8bf*)&w2_s[r][8 * (ch ^ (r & 7))] = v;
    }

    // edge indices (uniform within 16-lane group)
    int sr[4], tr[4];
    #pragma unroll
    for (int r = 0; r < 4; ++r) {
        int e = min(e_base + g * 4 + r, N_EDGES - 1);
        sr[r] = ei[e];
        tr[r] = ei[N_EDGES + e];
    }
    // vector QST gathers: cols [8c,8c+8) of src half / tgt half
    v8bf qsv[4], qtv[4];
    #pragma unroll
    for (int r = 0; r < 4; ++r) {
        qsv[r] = *(const v8bf*)(QSTB + (size_t)sr[r] * 256 + 8 * c);
        qtv[r] = *(const v8bf*)(QSTB + (size_t)tr[r] * 256 + 128 + 8 * c);
    }
    float4 b1a = *(const float4*)(b1 + 8 * c);
    float4 b1b = *(const float4*)(b1 + 8 * c + 4);
    float b1r[8] = {b1a.x, b1a.y, b1a.z, b1a.w, b1b.x, b1b.y, b1b.z, b1b.w};

    // A fragments from ef
    int er = min(e_base + c, N_EDGES - 1);
    const float* efr = ef + (size_t)er * D + g * 8;
    v8bf afrag[4];
    #pragma unroll
    for (int kc = 0; kc < 4; ++kc) afrag[kc] = cvt8(efr + kc * 32);

    // GEMM1: B row = 8c + jt
    v4f acc[8];
    #pragma unroll 2
    for (int jt = 0; jt < 8; ++jt) {
        const __bf16* wr = V3 + (size_t)(8 * c + jt) * 128 + g * 8;
        v4f a4 = (v4f){0.f, 0.f, 0.f, 0.f};
        #pragma unroll
        for (int kc = 0; kc < 4; ++kc)
            a4 = __builtin_amdgcn_mfma_f32_16x16x32_bf16(afrag[kc], *(const v8bf*)(wr + kc * 32), a4, 0, 0, 0);
        acc[jt] = a4;
    }

    // epilogue: fused gather-add + gelu -> one v8bf LDS store per row
    #pragma unroll
    for (int r = 0; r < 4; ++r) {
        int el = w * 16 + g * 4 + r;
        v8bf o;
        #pragma unroll
        for (int jt = 0; jt < 8; ++jt) {
            float v = acc[jt][r] + (float)qsv[r][jt] + (float)qtv[r][jt] + b1r[jt];
            o[jt] = (__bf16)gelu_exact(v);
        }
        *(v8bf*)&hc_s[el][8 * (c ^ (el & 7))] = o;
    }
    __syncthreads();

    // GEMM2: A = hc rows, B = W2 (both chunk-swizzled)
    v4f acc2 = (v4f){0.f, 0.f, 0.f, 0.f};
    int arow = w * 16 + c;
    #pragma unroll
    for (int kc = 0; kc < 4; ++kc) {
        int ch = g + 4 * kc;
        v8bf aa = *(const v8bf*)&hc_s[arow][8 * (ch ^ (c & 7))];
        v8bf bb = *(const v8bf*)&w2_s[c][8 * (ch ^ (c & 7))];
        acc2 = __builtin_amdgcn_mfma_f32_16x16x32_bf16(aa, bb, acc2, 0, 0, 0);
    }
    float b2c = b2[c];
    #pragma unroll
    for (int r = 0; r < 4; ++r) {
        int e = e_base + g * 4 + r;
        if (e < N_EDGES) out[(size_t)e * 16 + c] = acc2[r] + b2c;
    }
}

// ---------------------------------------------------------------------------
extern "C" void kernel_launch(void* const* d_in, const int* in_sizes, int n_in,
                              void* d_out, int out_size, void* d_ws, size_t ws_size,
                              hipStream_t stream) {
    const float* nf   = (const float*)d_in[0];
    const float* ef   = (const float*)d_in[1];
    const int*   ei   = (const int*)d_in[2];
    const int*   lab  = (const int*)d_in[3];
    const float* rel  = (const float*)d_in[4];
    const float* msgW = (const float*)d_in[5];
    const float* msgb = (const float*)d_in[6];
    const float* wih  = (const float*)d_in[7];
    const float* whh  = (const float*)d_in[8];
    const float* bih  = (const float*)d_in[9];
    const float* bhh  = (const float*)d_in[10];
    const float* W1   = (const float*)d_in[11];
    const float* b1   = (const float*)d_in[12];
    const float* W2   = (const float*)d_in[13];
    const float* b2   = (const float*)d_in[14];
    float* out = (float*)d_out;

    char* ws = (char*)d_ws;
    __bf16* WB      = (__bf16*)(ws);                  // 364.5 KB
    __bf16* RPB     = (__bf16*)(ws + 524288);         // 16 KB
    int*    offsets = (int*)(ws + 1048576);           // 200 KB (N+1)
    int*    counts  = (int*)(ws + 1310720);           // 200 KB
    int*    cursor  = (int*)(ws + 1572864);           // 200 KB
    int*    elist   = (int*)(ws + 1835008);           // 2 MB
    __bf16* PSTB    = (__bf16*)(ws + 4194304);        // 25.6 MB
    __bf16* AGG     = (__bf16*)(ws + 33554432);       // 12.8 MB
    __bf16* NFUB    = (__bf16*)(ws + 50331648);       // 12.8 MB
    __bf16* QSTB    = PSTB;                           // reuse after k_agg

    __bf16* WP1 = WB;
    __bf16* WQ1 = WB + 32768;
    __bf16* V3  = WB + 65536;
    __bf16* W2B = WB + 81920;
    __bf16* WIH = WB + 83968;
    __bf16* WHH = WB + 133120;

    int nblk = (N_NODES + 63) / 64;
    int eblk = (N_EDGES + 255) / 256;

    k_cvtw<<<712, 256, 0, stream>>>(msgW, W1, W2, wih, whh, WB);
    k_relpart<<<64, 128, 0, stream>>>(rel, msgW, msgb, RPB);
    hipMemsetAsync(counts, 0, N_NODES * sizeof(int), stream);
    k_hist<<<eblk, 256, 0, stream>>>(ei, counts);
    k_proj2_f32<<<nblk, 256, 0, stream>>>(nf, WP1, PSTB);
    k_scan<<<1, 256, 0, stream>>>(counts, offsets, cursor);
    k_scatter<<<eblk, 256, 0, stream>>>(ei, cursor, elist);
    k_agg<<<(N_NODES + 3) / 4, 256, 0, stream>>>(PSTB, RPB, ei, lab, offsets, elist, AGG);
    k_gru_mfma<<<nblk, 256, 0, stream>>>(AGG, nf, WIH, WHH, bih, bhh, NFUB);
    k_proj2_b16<<<nblk, 256, 0, stream>>>(NFUB, WQ1, QSTB);
    k_cls_mfma<<<(N_EDGES + 63) / 64, 256, 0, stream>>>(ef, QSTB, V3, b1, W2B, b2, ei, out);
}

// Round 10
// 591.942 us; speedup vs baseline: 1.0482x; 1.0462x over previous
//
#include <hip/hip_runtime.h>
#include <math.h>

#define N_NODES 50000
#define N_EDGES 500000
#define D 128
#define CAT 384

typedef __bf16 v8bf __attribute__((ext_vector_type(8)));
typedef __bf16 v2bf __attribute__((ext_vector_type(2)));
typedef float v4f __attribute__((ext_vector_type(4)));

// ---------------------------------------------------------------------------
// Fast transcendentals on the v_exp_f32 / v_rcp_f32 pipes.
// erf: Abramowitz-Stegun 7.1.26, |err| <= 1.5e-7 (exact at bf16 precision).
__device__ __forceinline__ float erf_fast(float x) {
    float ax = fabsf(x);
    float t = __builtin_amdgcn_rcpf(fmaf(0.3275911f, ax, 1.0f));
    float p = fmaf(1.061405429f, t, -1.453152027f);
    p = fmaf(p, t, 1.421413741f);
    p = fmaf(p, t, -0.284496736f);
    p = fmaf(p, t, 0.254829592f);
    p = p * t;
    float e = __expf(-ax * ax);          // v_exp_f32 path
    float r = 1.0f - p * e;
    return copysignf(r, x);
}

__device__ __forceinline__ float gelu_fast(float x) {
    return 0.5f * x * (1.0f + erf_fast(x * 0.70710678118654752440f));
}

__device__ __forceinline__ float sigmoid_fast(float x) {
    float e = __expf(-x);
    return __builtin_amdgcn_rcpf(1.0f + e);   // x->-inf: e=inf -> 0; x->+inf: -> 1
}

__device__ __forceinline__ float tanh_fast(float x) {
    float e = __expf(2.0f * x);
    return 1.0f - 2.0f * __builtin_amdgcn_rcpf(e + 1.0f);  // saturates correctly
}

__device__ __forceinline__ v8bf cvt8(const float* __restrict__ p) {
    float4 f0 = *(const float4*)p;
    float4 f1 = *(const float4*)(p + 4);
    v8bf r;
    r[0] = (__bf16)f0.x; r[1] = (__bf16)f0.y; r[2] = (__bf16)f0.z; r[3] = (__bf16)f0.w;
    r[4] = (__bf16)f1.x; r[5] = (__bf16)f1.y; r[6] = (__bf16)f1.z; r[7] = (__bf16)f1.w;
    return r;
}

// ---------------------------------------------------------------------------
// One-shot bf16 weight conversion (layouts = direct 16B B-fragments).
__global__ __launch_bounds__(256) void k_cvtw(const float* __restrict__ msgW,
                                              const float* __restrict__ W1,
                                              const float* __restrict__ W2,
                                              const float* __restrict__ wih,
                                              const float* __restrict__ whh,
                                              __bf16* __restrict__ WB) {
    int i = blockIdx.x * 256 + threadIdx.x;
    float v;
    if (i < 32768) {
        int j = i >> 7, k = i & 127;
        v = (j < 128) ? msgW[j * CAT + k] : msgW[(j - 128) * CAT + 128 + k];
    } else if (i < 65536) {
        int ii = i - 32768; int j = ii >> 7, k = ii & 127;
        v = (j < 128) ? W1[j * CAT + k] : W1[(j - 128) * CAT + 128 + k];
    } else if (i < 81920) {
        int ii = i - 65536; int j = ii >> 7, k = ii & 127;
        v = W1[j * CAT + 256 + k];
    } else if (i < 83968) {
        v = W2[i - 81920];
    } else if (i < 133120) {
        v = wih[i - 83968];
    } else {
        v = whh[i - 133120];
    }
    WB[i] = (__bf16)v;
}

// ---------------------------------------------------------------------------
__global__ void k_relpart(const float* __restrict__ rel_emb,
                          const float* __restrict__ msg_W,
                          const float* __restrict__ msg_b,
                          __bf16* __restrict__ RPB) {
    int r = blockIdx.x;
    int j = threadIdx.x;
    const float* er = rel_emb + r * D;
    const float* wr = msg_W + j * CAT + 2 * D;
    float acc = msg_b[j];
    #pragma unroll 8
    for (int k = 0; k < D; ++k) acc += er[k] * wr[k];
    RPB[r * D + j] = (__bf16)acc;
}

// ---------------------------------------------------------------------------
// MFMA node projection (fp32 input), output-col remap j = half*128 + 8c + jt.
__global__ __launch_bounds__(256) void k_proj2_f32(const float* __restrict__ in,
                                                   const __bf16* __restrict__ wb,
                                                   __bf16* __restrict__ out) {
    int t = threadIdx.x;
    int lane = t & 63, wid = t >> 6;
    int g = lane >> 4, c = lane & 15;
    int nbase = blockIdx.x * 64 + wid * 16;

    int nrow = min(nbase + c, N_NODES - 1);
    const float* ir = in + (size_t)nrow * D + g * 8;
    v8bf afrag[4];
    #pragma unroll
    for (int kc = 0; kc < 4; ++kc) afrag[kc] = cvt8(ir + kc * 32);

    #pragma unroll
    for (int half = 0; half < 2; ++half) {
        v4f acc[8];
        #pragma unroll 2
        for (int jt = 0; jt < 8; ++jt) {
            const __bf16* wr = wb + (size_t)(half * 128 + 8 * c + jt) * 128 + g * 8;
            v4f a4 = (v4f){0.f, 0.f, 0.f, 0.f};
            #pragma unroll
            for (int kc = 0; kc < 4; ++kc)
                a4 = __builtin_amdgcn_mfma_f32_16x16x32_bf16(afrag[kc], *(const v8bf*)(wr + kc * 32), a4, 0, 0, 0);
            acc[jt] = a4;
        }
        #pragma unroll
        for (int r = 0; r < 4; ++r) {
            int node = nbase + g * 4 + r;
            v8bf o;
            #pragma unroll
            for (int jt = 0; jt < 8; ++jt) o[jt] = (__bf16)acc[jt][r];
            if (node < N_NODES)
                *(v8bf*)(out + (size_t)node * 256 + half * 128 + 8 * c) = o;
        }
    }
}

// bf16-input variant (for NFUB -> QSTB).
__global__ __launch_bounds__(256) void k_proj2_b16(const __bf16* __restrict__ in,
                                                   const __bf16* __restrict__ wb,
                                                   __bf16* __restrict__ out) {
    int t = threadIdx.x;
    int lane = t & 63, wid = t >> 6;
    int g = lane >> 4, c = lane & 15;
    int nbase = blockIdx.x * 64 + wid * 16;

    int nrow = min(nbase + c, N_NODES - 1);
    const __bf16* ir = in + (size_t)nrow * D + g * 8;
    v8bf afrag[4];
    #pragma unroll
    for (int kc = 0; kc < 4; ++kc) afrag[kc] = *(const v8bf*)(ir + kc * 32);

    #pragma unroll
    for (int half = 0; half < 2; ++half) {
        v4f acc[8];
        #pragma unroll 2
        for (int jt = 0; jt < 8; ++jt) {
            const __bf16* wr = wb + (size_t)(half * 128 + 8 * c + jt) * 128 + g * 8;
            v4f a4 = (v4f){0.f, 0.f, 0.f, 0.f};
            #pragma unroll
            for (int kc = 0; kc < 4; ++kc)
                a4 = __builtin_amdgcn_mfma_f32_16x16x32_bf16(afrag[kc], *(const v8bf*)(wr + kc * 32), a4, 0, 0, 0);
            acc[jt] = a4;
        }
        #pragma unroll
        for (int r = 0; r < 4; ++r) {
            int node = nbase + g * 4 + r;
            v8bf o;
            #pragma unroll
            for (int jt = 0; jt < 8; ++jt) o[jt] = (__bf16)acc[jt][r];
            if (node < N_NODES)
                *(v8bf*)(out + (size_t)node * 256 + half * 128 + 8 * c) = o;
        }
    }
}

// ---------------------------------------------------------------------------
// CSR build: histogram -> scan -> scatter.
__global__ __launch_bounds__(256) void k_hist(const int* __restrict__ ei,
                                              int* __restrict__ counts) {
    int e = blockIdx.x * 256 + threadIdx.x;
    if (e < N_EDGES) atomicAdd(&counts[ei[N_EDGES + e]], 1);
}

__global__ __launch_bounds__(256) void k_scan(const int* __restrict__ counts,
                                              int* __restrict__ offsets,
                                              int* __restrict__ cursor) {
    __shared__ int part[256];
    int t = threadIdx.x;
    const int CH = 196;
    int lo = t * CH, hi = min(lo + CH, N_NODES);
    int s = 0;
    for (int i = lo; i < hi; ++i) s += counts[i];
    part[t] = s;
    __syncthreads();
    for (int d = 1; d < 256; d <<= 1) {
        int v = (t >= d) ? part[t - d] : 0;
        __syncthreads();
        part[t] += v;
        __syncthreads();
    }
    int run = (t == 0) ? 0 : part[t - 1];
    for (int i = lo; i < hi; ++i) {
        offsets[i] = run;
        cursor[i] = run;
        run += counts[i];
    }
    if (t == 255) offsets[N_NODES] = run;
}

__global__ __launch_bounds__(256) void k_scatter(const int* __restrict__ ei,
                                                 int* __restrict__ cursor,
                                                 int* __restrict__ elist) {
    int e = blockIdx.x * 256 + threadIdx.x;
    if (e < N_EDGES) {
        int slot = atomicAdd(&cursor[ei[N_EDGES + e]], 1);
        elist[slot] = e;
    }
}

// ---------------------------------------------------------------------------
// Aggregation, atomic-free; one wave per node; index-prefetch pipeline.
__global__ __launch_bounds__(256) void k_agg(const __bf16* __restrict__ PSTB,
                                             const __bf16* __restrict__ RPB,
                                             const int* __restrict__ ei,
                                             const int* __restrict__ lab,
                                             const int* __restrict__ offsets,
                                             const int* __restrict__ elist,
                                             __bf16* __restrict__ agg) {
    int t = threadIdx.x;
    int wid = t >> 6, lane = t & 63;
    int n = blockIdx.x * 4 + wid;
    if (n >= N_NODES) return;
    int beg = offsets[n], end = offsets[n + 1];

    v2bf ptv = *(const v2bf*)(PSTB + (size_t)n * 256 + 128 + lane * 2);
    float pt0 = (float)ptv[0], pt1 = (float)ptv[1];

    float a0 = 0.f, a1 = 0.f;
    int idx = beg;
    int s_nx = 0, l_nx = 0;
    if (idx < end) { int e = elist[idx]; s_nx = ei[e]; l_nx = lab[e]; }
    while (idx < end) {
        int s = s_nx, l = l_nx;
        v2bf ps = *(const v2bf*)(PSTB + (size_t)s * 256 + lane * 2);
        v2bf rp = *(const v2bf*)(RPB + (size_t)l * D + lane * 2);
        ++idx;
        if (idx < end) { int e = elist[idx]; s_nx = ei[e]; l_nx = lab[e]; }
        a0 += gelu_fast((float)ps[0] + pt0 + (float)rp[0]);
        a1 += gelu_fast((float)ps[1] + pt1 + (float)rp[1]);
    }
    v2bf o; o[0] = (__bf16)a0; o[1] = (__bf16)a1;
    *(v2bf*)(agg + (size_t)n * D + lane * 2) = o;
}

// ---------------------------------------------------------------------------
// MFMA GRU, output-col remap j = 8c + jt; fast sigmoid/tanh epilogue.
__global__ __launch_bounds__(256) void k_gru_mfma(const __bf16* __restrict__ agg,
                                                  const float* __restrict__ nf,
                                                  const __bf16* __restrict__ WIH,
                                                  const __bf16* __restrict__ WHH,
                                                  const float* __restrict__ b_ih,
                                                  const float* __restrict__ b_hh,
                                                  __bf16* __restrict__ nfu) {
    int t = threadIdx.x;
    int lane = t & 63, wid = t >> 6;
    int g = lane >> 4, c = lane & 15;
    int nbase = blockIdx.x * 64 + wid * 16;

    int nrow = min(nbase + c, N_NODES - 1);
    const __bf16* ar = agg + (size_t)nrow * D + g * 8;
    const float* hr = nf + (size_t)nrow * D + g * 8;
    v8bf afrag[4], hfrag[4];
    #pragma unroll
    for (int kc = 0; kc < 4; ++kc) {
        afrag[kc] = *(const v8bf*)(ar + kc * 32);
        hfrag[kc] = cvt8(hr + kc * 32);
    }

    float h8[4][8];
    #pragma unroll
    for (int r = 0; r < 4; ++r) {
        int node = min(nbase + g * 4 + r, N_NODES - 1);
        float4 f0 = *(const float4*)(nf + (size_t)node * D + 8 * c);
        float4 f1 = *(const float4*)(nf + (size_t)node * D + 8 * c + 4);
        h8[r][0]=f0.x; h8[r][1]=f0.y; h8[r][2]=f0.z; h8[r][3]=f0.w;
        h8[r][4]=f1.x; h8[r][5]=f1.y; h8[r][6]=f1.z; h8[r][7]=f1.w;
    }

    v8bf o[4];
    for (int jt = 0; jt < 8; ++jt) {
        int j = 8 * c + jt;
        const __bf16* wir = WIH + (size_t)j * 128 + g * 8;
        const __bf16* whr = WHH + (size_t)j * 128 + g * 8;
        v4f a_ir = (v4f){0.f,0.f,0.f,0.f}, a_iz = a_ir, a_in = a_ir;
        v4f a_hr = a_ir, a_hz = a_ir, a_hn = a_ir;
        #pragma unroll
        for (int kc = 0; kc < 4; ++kc) {
            a_ir = __builtin_amdgcn_mfma_f32_16x16x32_bf16(afrag[kc], *(const v8bf*)(wir + kc * 32), a_ir, 0, 0, 0);
            a_iz = __builtin_amdgcn_mfma_f32_16x16x32_bf16(afrag[kc], *(const v8bf*)(wir + 128 * 128 + kc * 32), a_iz, 0, 0, 0);
            a_in = __builtin_amdgcn_mfma_f32_16x16x32_bf16(afrag[kc], *(const v8bf*)(wir + 256 * 128 + kc * 32), a_in, 0, 0, 0);
            a_hr = __builtin_amdgcn_mfma_f32_16x16x32_bf16(hfrag[kc], *(const v8bf*)(whr + kc * 32), a_hr, 0, 0, 0);
            a_hz = __builtin_amdgcn_mfma_f32_16x16x32_bf16(hfrag[kc], *(const v8bf*)(whr + 128 * 128 + kc * 32), a_hz, 0, 0, 0);
            a_hn = __builtin_amdgcn_mfma_f32_16x16x32_bf16(hfrag[kc], *(const v8bf*)(whr + 256 * 128 + kc * 32), a_hn, 0, 0, 0);
        }
        float bir = b_ih[j], biz = b_ih[128 + j], bin = b_ih[256 + j];
        float bhr = b_hh[j], bhz = b_hh[128 + j], bhn = b_hh[256 + j];
        #pragma unroll
        for (int r = 0; r < 4; ++r) {
            float irv = a_ir[r] + bir, hrv = a_hr[r] + bhr;
            float izv = a_iz[r] + biz, hzv = a_hz[r] + bhz;
            float inv = a_in[r] + bin, hnv = a_hn[r] + bhn;
            float rg = sigmoid_fast(irv + hrv);
            float zg = sigmoid_fast(izv + hzv);
            float ng = tanh_fast(inv + rg * hnv);
            o[r][jt] = (__bf16)((1.f - zg) * ng + zg * h8[r][jt]);
        }
    }
    #pragma unroll
    for (int r = 0; r < 4; ++r) {
        int node = nbase + g * 4 + r;
        if (node < N_NODES) *(v8bf*)(nfu + (size_t)node * D + 8 * c) = o[r];
    }
}

// ---------------------------------------------------------------------------
// MFMA classifier, output-col remap j = 8c + jt (r9 structure, fast gelu).
__global__ __launch_bounds__(256) void k_cls_mfma(const float* __restrict__ ef,
                                                  const __bf16* __restrict__ QSTB,
                                                  const __bf16* __restrict__ V3,
                                                  const float* __restrict__ b1,
                                                  const __bf16* __restrict__ W2B,
                                                  const float* __restrict__ b2,
                                                  const int* __restrict__ ei,
                                                  float* __restrict__ out) {
    __shared__ __align__(16) __bf16 hc_s[64][128];
    __shared__ __align__(16) __bf16 w2_s[16][128];
    int t = threadIdx.x;
    int lane = t & 63, w = t >> 6;
    int g = lane >> 4, c = lane & 15;
    int e0 = blockIdx.x * 64;
    int e_base = e0 + w * 16;

    // stage W2 chunk-swizzled: 256 threads x one 16B chunk
    {
        int r = t >> 4, ch = t & 15;
        v8bf v = *(const v8bf*)(W2B + r * 128 + ch * 8);
        *(v8bf*)&w2_s[r][8 * (ch ^ (r & 7))] = v;
    }

    int sr[4], tr[4];
    #pragma unroll
    for (int r = 0; r < 4; ++r) {
        int e = min(e_base + g * 4 + r, N_EDGES - 1);
        sr[r] = ei[e];
        tr[r] = ei[N_EDGES + e];
    }
    v8bf qsv[4], qtv[4];
    #pragma unroll
    for (int r = 0; r < 4; ++r) {
        qsv[r] = *(const v8bf*)(QSTB + (size_t)sr[r] * 256 + 8 * c);
        qtv[r] = *(const v8bf*)(QSTB + (size_t)tr[r] * 256 + 128 + 8 * c);
    }
    float4 b1a = *(const float4*)(b1 + 8 * c);
    float4 b1b = *(const float4*)(b1 + 8 * c + 4);
    float b1r[8] = {b1a.x, b1a.y, b1a.z, b1a.w, b1b.x, b1b.y, b1b.z, b1b.w};

    int er = min(e_base + c, N_EDGES - 1);
    const float* efr = ef + (size_t)er * D + g * 8;
    v8bf afrag[4];
    #pragma unroll
    for (int kc = 0; kc < 4; ++kc) afrag[kc] = cvt8(efr + kc * 32);

    v4f acc[8];
    #pragma unroll 2
    for (int jt = 0; jt < 8; ++jt) {
        const __bf16* wr = V3 + (size_t)(8 * c + jt) * 128 + g * 8;
        v4f a4 = (v4f){0.f, 0.f, 0.f, 0.f};
        #pragma unroll
        for (int kc = 0; kc < 4; ++kc)
            a4 = __builtin_amdgcn_mfma_f32_16x16x32_bf16(afrag[kc], *(const v8bf*)(wr + kc * 32), a4, 0, 0, 0);
        acc[jt] = a4;
    }

    #pragma unroll
    for (int r = 0; r < 4; ++r) {
        int el = w * 16 + g * 4 + r;
        v8bf o;
        #pragma unroll
        for (int jt = 0; jt < 8; ++jt) {
            float v = acc[jt][r] + (float)qsv[r][jt] + (float)qtv[r][jt] + b1r[jt];
            o[jt] = (__bf16)gelu_fast(v);
        }
        *(v8bf*)&hc_s[el][8 * (c ^ (el & 7))] = o;
    }
    __syncthreads();

    v4f acc2 = (v4f){0.f, 0.f, 0.f, 0.f};
    int arow = w * 16 + c;
    #pragma unroll
    for (int kc = 0; kc < 4; ++kc) {
        int ch = g + 4 * kc;
        v8bf aa = *(const v8bf*)&hc_s[arow][8 * (ch ^ (c & 7))];
        v8bf bb = *(const v8bf*)&w2_s[c][8 * (ch ^ (c & 7))];
        acc2 = __builtin_amdgcn_mfma_f32_16x16x32_bf16(aa, bb, acc2, 0, 0, 0);
    }
    float b2c = b2[c];
    #pragma unroll
    for (int r = 0; r < 4; ++r) {
        int e = e_base + g * 4 + r;
        if (e < N_EDGES) out[(size_t)e * 16 + c] = acc2[r] + b2c;
    }
}

// ---------------------------------------------------------------------------
extern "C" void kernel_launch(void* const* d_in, const int* in_sizes, int n_in,
                              void* d_out, int out_size, void* d_ws, size_t ws_size,
                              hipStream_t stream) {
    const float* nf   = (const float*)d_in[0];
    const float* ef   = (const float*)d_in[1];
    const int*   ei   = (const int*)d_in[2];
    const int*   lab  = (const int*)d_in[3];
    const float* rel  = (const float*)d_in[4];
    const float* msgW = (const float*)d_in[5];
    const float* msgb = (const float*)d_in[6];
    const float* wih  = (const float*)d_in[7];
    const float* whh  = (const float*)d_in[8];
    const float* bih  = (const float*)d_in[9];
    const float* bhh  = (const float*)d_in[10];
    const float* W1   = (const float*)d_in[11];
    const float* b1   = (const float*)d_in[12];
    const float* W2   = (const float*)d_in[13];
    const float* b2   = (const float*)d_in[14];
    float* out = (float*)d_out;

    char* ws = (char*)d_ws;
    __bf16* WB      = (__bf16*)(ws);                  // 364.5 KB
    __bf16* RPB     = (__bf16*)(ws + 524288);         // 16 KB
    int*    offsets = (int*)(ws + 1048576);           // 200 KB (N+1)
    int*    counts  = (int*)(ws + 1310720);           // 200 KB
    int*    cursor  = (int*)(ws + 1572864);           // 200 KB
    int*    elist   = (int*)(ws + 1835008);           // 2 MB
    __bf16* PSTB    = (__bf16*)(ws + 4194304);        // 25.6 MB
    __bf16* AGG     = (__bf16*)(ws + 33554432);       // 12.8 MB
    __bf16* NFUB    = (__bf16*)(ws + 50331648);       // 12.8 MB
    __bf16* QSTB    = PSTB;                           // reuse after k_agg

    __bf16* WP1 = WB;
    __bf16* WQ1 = WB + 32768;
    __bf16* V3  = WB + 65536;
    __bf16* W2B = WB + 81920;
    __bf16* WIH = WB + 83968;
    __bf16* WHH = WB + 133120;

    int nblk = (N_NODES + 63) / 64;
    int eblk = (N_EDGES + 255) / 256;

    k_cvtw<<<712, 256, 0, stream>>>(msgW, W1, W2, wih, whh, WB);
    k_relpart<<<64, 128, 0, stream>>>(rel, msgW, msgb, RPB);
    hipMemsetAsync(counts, 0, N_NODES * sizeof(int), stream);
    k_hist<<<eblk, 256, 0, stream>>>(ei, counts);
    k_proj2_f32<<<nblk, 256, 0, stream>>>(nf, WP1, PSTB);
    k_scan<<<1, 256, 0, stream>>>(counts, offsets, cursor);
    k_scatter<<<eblk, 256, 0, stream>>>(ei, cursor, elist);
    k_agg<<<(N_NODES + 3) / 4, 256, 0, stream>>>(PSTB, RPB, ei, lab, offsets, elist, AGG);
    k_gru_mfma<<<nblk, 256, 0, stream>>>(AGG, nf, WIH, WHH, bih, bhh, NFUB);
    k_proj2_b16<<<nblk, 256, 0, stream>>>(NFUB, WQ1, QSTB);
    k_cls_mfma<<<(N_EDGES + 63) / 64, 256, 0, stream>>>(ef, QSTB, V3, b1, W2B, b2, ei, out);
}

// Round 11
// 590.813 us; speedup vs baseline: 1.0502x; 1.0019x over previous
//
#include <hip/hip_runtime.h>
#include <math.h>

#define N_NODES 50000
#define N_EDGES 500000
#define D 128
#define CAT 384

typedef __bf16 v8bf __attribute__((ext_vector_type(8)));
typedef __bf16 v2bf __attribute__((ext_vector_type(2)));
typedef float v4f __attribute__((ext_vector_type(4)));

// ---------------------------------------------------------------------------
// Fast transcendentals on the v_exp_f32 / v_rcp_f32 pipes.
__device__ __forceinline__ float erf_fast(float x) {
    float ax = fabsf(x);
    float t = __builtin_amdgcn_rcpf(fmaf(0.3275911f, ax, 1.0f));
    float p = fmaf(1.061405429f, t, -1.453152027f);
    p = fmaf(p, t, 1.421413741f);
    p = fmaf(p, t, -0.284496736f);
    p = fmaf(p, t, 0.254829592f);
    p = p * t;
    float e = __expf(-ax * ax);
    float r = 1.0f - p * e;
    return copysignf(r, x);
}

__device__ __forceinline__ float gelu_fast(float x) {
    return 0.5f * x * (1.0f + erf_fast(x * 0.70710678118654752440f));
}

__device__ __forceinline__ float sigmoid_fast(float x) {
    float e = __expf(-x);
    return __builtin_amdgcn_rcpf(1.0f + e);
}

__device__ __forceinline__ float tanh_fast(float x) {
    float e = __expf(2.0f * x);
    return 1.0f - 2.0f * __builtin_amdgcn_rcpf(e + 1.0f);
}

__device__ __forceinline__ v8bf cvt8(const float* __restrict__ p) {
    float4 f0 = *(const float4*)p;
    float4 f1 = *(const float4*)(p + 4);
    v8bf r;
    r[0] = (__bf16)f0.x; r[1] = (__bf16)f0.y; r[2] = (__bf16)f0.z; r[3] = (__bf16)f0.w;
    r[4] = (__bf16)f1.x; r[5] = (__bf16)f1.y; r[6] = (__bf16)f1.z; r[7] = (__bf16)f1.w;
    return r;
}

// ---------------------------------------------------------------------------
// Fused pre-pass: [0,712) weight cvt | [712,744) relpart | [744,...) histogram.
__global__ __launch_bounds__(256) void k_pre(const float* __restrict__ msgW,
                                             const float* __restrict__ W1,
                                             const float* __restrict__ W2,
                                             const float* __restrict__ wih,
                                             const float* __restrict__ whh,
                                             __bf16* __restrict__ WB,
                                             const float* __restrict__ rel_emb,
                                             const float* __restrict__ msg_b,
                                             __bf16* __restrict__ RPB,
                                             const int* __restrict__ ei,
                                             int* __restrict__ counts) {
    int bid = blockIdx.x;
    int t = threadIdx.x;
    if (bid < 712) {
        int i = bid * 256 + t;
        float v;
        if (i < 32768) {
            int j = i >> 7, k = i & 127;
            v = (j < 128) ? msgW[j * CAT + k] : msgW[(j - 128) * CAT + 128 + k];
        } else if (i < 65536) {
            int ii = i - 32768; int j = ii >> 7, k = ii & 127;
            v = (j < 128) ? W1[j * CAT + k] : W1[(j - 128) * CAT + 128 + k];
        } else if (i < 81920) {
            int ii = i - 65536; int j = ii >> 7, k = ii & 127;
            v = W1[j * CAT + 256 + k];
        } else if (i < 83968) {
            v = W2[i - 81920];
        } else if (i < 133120) {
            v = wih[i - 83968];
        } else {
            v = whh[i - 133120];
        }
        WB[i] = (__bf16)v;
    } else if (bid < 744) {
        int r = (bid - 712) * 2 + (t >> 7);
        int j = t & 127;
        const float* er = rel_emb + r * D;
        const float* wr = msgW + j * CAT + 2 * D;
        float acc = msg_b[j];
        #pragma unroll 8
        for (int k = 0; k < D; ++k) acc += er[k] * wr[k];
        RPB[r * D + j] = (__bf16)acc;
    } else {
        int e = (bid - 744) * 256 + t;
        if (e < N_EDGES) atomicAdd(&counts[ei[N_EDGES + e]], 1);
    }
}

// ---------------------------------------------------------------------------
// MFMA node projection (fp32 input), output-col remap j = half*128 + 8c + jt.
__global__ __launch_bounds__(256) void k_proj2_f32(const float* __restrict__ in,
                                                   const __bf16* __restrict__ wb,
                                                   __bf16* __restrict__ out) {
    int t = threadIdx.x;
    int lane = t & 63, wid = t >> 6;
    int g = lane >> 4, c = lane & 15;
    int nbase = blockIdx.x * 64 + wid * 16;

    int nrow = min(nbase + c, N_NODES - 1);
    const float* ir = in + (size_t)nrow * D + g * 8;
    v8bf afrag[4];
    #pragma unroll
    for (int kc = 0; kc < 4; ++kc) afrag[kc] = cvt8(ir + kc * 32);

    #pragma unroll
    for (int half = 0; half < 2; ++half) {
        v4f acc[8];
        #pragma unroll 2
        for (int jt = 0; jt < 8; ++jt) {
            const __bf16* wr = wb + (size_t)(half * 128 + 8 * c + jt) * 128 + g * 8;
            v4f a4 = (v4f){0.f, 0.f, 0.f, 0.f};
            #pragma unroll
            for (int kc = 0; kc < 4; ++kc)
                a4 = __builtin_amdgcn_mfma_f32_16x16x32_bf16(afrag[kc], *(const v8bf*)(wr + kc * 32), a4, 0, 0, 0);
            acc[jt] = a4;
        }
        #pragma unroll
        for (int r = 0; r < 4; ++r) {
            int node = nbase + g * 4 + r;
            v8bf o;
            #pragma unroll
            for (int jt = 0; jt < 8; ++jt) o[jt] = (__bf16)acc[jt][r];
            if (node < N_NODES)
                *(v8bf*)(out + (size_t)node * 256 + half * 128 + 8 * c) = o;
        }
    }
}

// bf16-input variant (for NFUB -> QSTB).
__global__ __launch_bounds__(256) void k_proj2_b16(const __bf16* __restrict__ in,
                                                   const __bf16* __restrict__ wb,
                                                   __bf16* __restrict__ out) {
    int t = threadIdx.x;
    int lane = t & 63, wid = t >> 6;
    int g = lane >> 4, c = lane & 15;
    int nbase = blockIdx.x * 64 + wid * 16;

    int nrow = min(nbase + c, N_NODES - 1);
    const __bf16* ir = in + (size_t)nrow * D + g * 8;
    v8bf afrag[4];
    #pragma unroll
    for (int kc = 0; kc < 4; ++kc) afrag[kc] = *(const v8bf*)(ir + kc * 32);

    #pragma unroll
    for (int half = 0; half < 2; ++half) {
        v4f acc[8];
        #pragma unroll 2
        for (int jt = 0; jt < 8; ++jt) {
            const __bf16* wr = wb + (size_t)(half * 128 + 8 * c + jt) * 128 + g * 8;
            v4f a4 = (v4f){0.f, 0.f, 0.f, 0.f};
            #pragma unroll
            for (int kc = 0; kc < 4; ++kc)
                a4 = __builtin_amdgcn_mfma_f32_16x16x32_bf16(afrag[kc], *(const v8bf*)(wr + kc * 32), a4, 0, 0, 0);
            acc[jt] = a4;
        }
        #pragma unroll
        for (int r = 0; r < 4; ++r) {
            int node = nbase + g * 4 + r;
            v8bf o;
            #pragma unroll
            for (int jt = 0; jt < 8; ++jt) o[jt] = (__bf16)acc[jt][r];
            if (node < N_NODES)
                *(v8bf*)(out + (size_t)node * 256 + half * 128 + 8 * c) = o;
        }
    }
}

// ---------------------------------------------------------------------------
__global__ __launch_bounds__(256) void k_scan(const int* __restrict__ counts,
                                              int* __restrict__ offsets,
                                              int* __restrict__ cursor) {
    __shared__ int part[256];
    int t = threadIdx.x;
    const int CH = 196;
    int lo = t * CH, hi = min(lo + CH, N_NODES);
    int s = 0;
    for (int i = lo; i < hi; ++i) s += counts[i];
    part[t] = s;
    __syncthreads();
    for (int d = 1; d < 256; d <<= 1) {
        int v = (t >= d) ? part[t - d] : 0;
        __syncthreads();
        part[t] += v;
        __syncthreads();
    }
    int run = (t == 0) ? 0 : part[t - 1];
    for (int i = lo; i < hi; ++i) {
        offsets[i] = run;
        cursor[i] = run;
        run += counts[i];
    }
    if (t == 255) offsets[N_NODES] = run;
}

__global__ __launch_bounds__(256) void k_scatter(const int* __restrict__ ei,
                                                 int* __restrict__ cursor,
                                                 int* __restrict__ elist) {
    int e = blockIdx.x * 256 + threadIdx.x;
    if (e < N_EDGES) {
        int slot = atomicAdd(&cursor[ei[N_EDGES + e]], 1);
        elist[slot] = e;
    }
}

// ---------------------------------------------------------------------------
// Aggregation, atomic-free; 2-deep index prefetch + 1-deep row-data prefetch.
__global__ __launch_bounds__(256) void k_agg(const __bf16* __restrict__ PSTB,
                                             const __bf16* __restrict__ RPB,
                                             const int* __restrict__ ei,
                                             const int* __restrict__ lab,
                                             const int* __restrict__ offsets,
                                             const int* __restrict__ elist,
                                             __bf16* __restrict__ agg) {
    int t = threadIdx.x;
    int wid = t >> 6, lane = t & 63;
    int n = blockIdx.x * 4 + wid;
    if (n >= N_NODES) return;
    int beg = offsets[n], end = offsets[n + 1];

    v2bf ptv = *(const v2bf*)(PSTB + (size_t)n * 256 + 128 + lane * 2);
    float pt0 = (float)ptv[0], pt1 = (float)ptv[1];

    float a0 = 0.f, a1 = 0.f;
    v2bf ps0 = {}, rp0 = {};
    int s1 = 0, l1 = 0;
    if (beg < end) {
        int e = elist[beg]; int s = ei[e]; int l = lab[e];
        ps0 = *(const v2bf*)(PSTB + (size_t)s * 256 + lane * 2);
        rp0 = *(const v2bf*)(RPB + (size_t)l * D + lane * 2);
    }
    if (beg + 1 < end) {
        int e = elist[beg + 1]; s1 = ei[e]; l1 = lab[e];
    }
    for (int idx = beg; idx < end; ++idx) {
        v2bf ps = ps0, rp = rp0;
        if (idx + 1 < end) {
            ps0 = *(const v2bf*)(PSTB + (size_t)s1 * 256 + lane * 2);
            rp0 = *(const v2bf*)(RPB + (size_t)l1 * D + lane * 2);
        }
        if (idx + 2 < end) {
            int e = elist[idx + 2]; s1 = ei[e]; l1 = lab[e];
        }
        a0 += gelu_fast((float)ps[0] + pt0 + (float)rp[0]);
        a1 += gelu_fast((float)ps[1] + pt1 + (float)rp[1]);
    }
    v2bf o; o[0] = (__bf16)a0; o[1] = (__bf16)a1;
    *(v2bf*)(agg + (size_t)n * D + lane * 2) = o;
}

// ---------------------------------------------------------------------------
// MFMA GRU (unchanged structure, fast epilogue).
__global__ __launch_bounds__(256) void k_gru_mfma(const __bf16* __restrict__ agg,
                                                  const float* __restrict__ nf,
                                                  const __bf16* __restrict__ WIH,
                                                  const __bf16* __restrict__ WHH,
                                                  const float* __restrict__ b_ih,
                                                  const float* __restrict__ b_hh,
                                                  __bf16* __restrict__ nfu) {
    int t = threadIdx.x;
    int lane = t & 63, wid = t >> 6;
    int g = lane >> 4, c = lane & 15;
    int nbase = blockIdx.x * 64 + wid * 16;

    int nrow = min(nbase + c, N_NODES - 1);
    const __bf16* ar = agg + (size_t)nrow * D + g * 8;
    const float* hr = nf + (size_t)nrow * D + g * 8;
    v8bf afrag[4], hfrag[4];
    #pragma unroll
    for (int kc = 0; kc < 4; ++kc) {
        afrag[kc] = *(const v8bf*)(ar + kc * 32);
        hfrag[kc] = cvt8(hr + kc * 32);
    }

    float h8[4][8];
    #pragma unroll
    for (int r = 0; r < 4; ++r) {
        int node = min(nbase + g * 4 + r, N_NODES - 1);
        float4 f0 = *(const float4*)(nf + (size_t)node * D + 8 * c);
        float4 f1 = *(const float4*)(nf + (size_t)node * D + 8 * c + 4);
        h8[r][0]=f0.x; h8[r][1]=f0.y; h8[r][2]=f0.z; h8[r][3]=f0.w;
        h8[r][4]=f1.x; h8[r][5]=f1.y; h8[r][6]=f1.z; h8[r][7]=f1.w;
    }

    v8bf o[4];
    for (int jt = 0; jt < 8; ++jt) {
        int j = 8 * c + jt;
        const __bf16* wir = WIH + (size_t)j * 128 + g * 8;
        const __bf16* whr = WHH + (size_t)j * 128 + g * 8;
        v4f a_ir = (v4f){0.f,0.f,0.f,0.f}, a_iz = a_ir, a_in = a_ir;
        v4f a_hr = a_ir, a_hz = a_ir, a_hn = a_ir;
        #pragma unroll
        for (int kc = 0; kc < 4; ++kc) {
            a_ir = __builtin_amdgcn_mfma_f32_16x16x32_bf16(afrag[kc], *(const v8bf*)(wir + kc * 32), a_ir, 0, 0, 0);
            a_iz = __builtin_amdgcn_mfma_f32_16x16x32_bf16(afrag[kc], *(const v8bf*)(wir + 128 * 128 + kc * 32), a_iz, 0, 0, 0);
            a_in = __builtin_amdgcn_mfma_f32_16x16x32_bf16(afrag[kc], *(const v8bf*)(wir + 256 * 128 + kc * 32), a_in, 0, 0, 0);
            a_hr = __builtin_amdgcn_mfma_f32_16x16x32_bf16(hfrag[kc], *(const v8bf*)(whr + kc * 32), a_hr, 0, 0, 0);
            a_hz = __builtin_amdgcn_mfma_f32_16x16x32_bf16(hfrag[kc], *(const v8bf*)(whr + 128 * 128 + kc * 32), a_hz, 0, 0, 0);
            a_hn = __builtin_amdgcn_mfma_f32_16x16x32_bf16(hfrag[kc], *(const v8bf*)(whr + 256 * 128 + kc * 32), a_hn, 0, 0, 0);
        }
        float bir = b_ih[j], biz = b_ih[128 + j], bin = b_ih[256 + j];
        float bhr = b_hh[j], bhz = b_hh[128 + j], bhn = b_hh[256 + j];
        #pragma unroll
        for (int r = 0; r < 4; ++r) {
            float irv = a_ir[r] + bir, hrv = a_hr[r] + bhr;
            float izv = a_iz[r] + biz, hzv = a_hz[r] + bhz;
            float inv = a_in[r] + bin, hnv = a_hn[r] + bhn;
            float rg = sigmoid_fast(irv + hrv);
            float zg = sigmoid_fast(izv + hzv);
            float ng = tanh_fast(inv + rg * hnv);
            o[r][jt] = (__bf16)((1.f - zg) * ng + zg * h8[r][jt]);
        }
    }
    #pragma unroll
    for (int r = 0; r < 4; ++r) {
        int node = nbase + g * 4 + r;
        if (node < N_NODES) *(v8bf*)(nfu + (size_t)node * D + 8 * c) = o[r];
    }
}

// ---------------------------------------------------------------------------
// MFMA classifier v4: ef issued first; no block barrier (hc round-trip is
// wave-local: wave w writes and reads only rows [16w,16w+16)); W2 B-frags
// direct from global (4KB, L1-hot).
__global__ __launch_bounds__(256) void k_cls_mfma(const float* __restrict__ ef,
                                                  const __bf16* __restrict__ QSTB,
                                                  const __bf16* __restrict__ V3,
                                                  const float* __restrict__ b1,
                                                  const __bf16* __restrict__ W2B,
                                                  const float* __restrict__ b2,
                                                  const int* __restrict__ ei,
                                                  float* __restrict__ out) {
    __shared__ __align__(16) __bf16 hc_s[64][128];
    int t = threadIdx.x;
    int lane = t & 63, w = t >> 6;
    int g = lane >> 4, c = lane & 15;
    int e0 = blockIdx.x * 64;
    int e_base = e0 + w * 16;

    // (1) longest-latency first: ef HBM stream
    int er = min(e_base + c, N_EDGES - 1);
    const float* efr = ef + (size_t)er * D + g * 8;
    float4 efraw[8];
    #pragma unroll
    for (int kc = 0; kc < 4; ++kc) {
        efraw[2 * kc]     = *(const float4*)(efr + kc * 32);
        efraw[2 * kc + 1] = *(const float4*)(efr + kc * 32 + 4);
    }

    // (2) edge indices -> QST gathers (L2/L3)
    int sr[4], tr[4];
    #pragma unroll
    for (int r = 0; r < 4; ++r) {
        int e = min(e_base + g * 4 + r, N_EDGES - 1);
        sr[r] = ei[e];
        tr[r] = ei[N_EDGES + e];
    }
    v8bf qsv[4], qtv[4];
    #pragma unroll
    for (int r = 0; r < 4; ++r) {
        qsv[r] = *(const v8bf*)(QSTB + (size_t)sr[r] * 256 + 8 * c);
        qtv[r] = *(const v8bf*)(QSTB + (size_t)tr[r] * 256 + 128 + 8 * c);
    }
    float4 b1a = *(const float4*)(b1 + 8 * c);
    float4 b1b = *(const float4*)(b1 + 8 * c + 4);
    float b1r[8] = {b1a.x, b1a.y, b1a.z, b1a.w, b1b.x, b1b.y, b1b.z, b1b.w};

    // (3) cvt ef -> A fragments (waits only on efraw)
    v8bf afrag[4];
    #pragma unroll
    for (int kc = 0; kc < 4; ++kc) {
        v8bf a;
        float4 f0 = efraw[2 * kc], f1 = efraw[2 * kc + 1];
        a[0] = (__bf16)f0.x; a[1] = (__bf16)f0.y; a[2] = (__bf16)f0.z; a[3] = (__bf16)f0.w;
        a[4] = (__bf16)f1.x; a[5] = (__bf16)f1.y; a[6] = (__bf16)f1.z; a[7] = (__bf16)f1.w;
        afrag[kc] = a;
    }

    // (4) GEMM1: B streamed from V3 (L1-hot, 32KB), fully unrolled
    v4f acc[8];
    #pragma unroll
    for (int jt = 0; jt < 8; ++jt) {
        const __bf16* wr = V3 + (size_t)(8 * c + jt) * 128 + g * 8;
        v4f a4 = (v4f){0.f, 0.f, 0.f, 0.f};
        #pragma unroll
        for (int kc = 0; kc < 4; ++kc)
            a4 = __builtin_amdgcn_mfma_f32_16x16x32_bf16(afrag[kc], *(const v8bf*)(wr + kc * 32), a4, 0, 0, 0);
        acc[jt] = a4;
    }

    // (5) epilogue -> wave-local LDS (swizzled); no block barrier needed
    #pragma unroll
    for (int r = 0; r < 4; ++r) {
        int el = w * 16 + g * 4 + r;
        v8bf o;
        #pragma unroll
        for (int jt = 0; jt < 8; ++jt) {
            float v = acc[jt][r] + (float)qsv[r][jt] + (float)qtv[r][jt] + b1r[jt];
            o[jt] = (__bf16)gelu_fast(v);
        }
        *(v8bf*)&hc_s[el][8 * (c ^ (el & 7))] = o;
    }

    // (6) GEMM2: A from wave-local hc rows, B direct from W2B global
    v4f acc2 = (v4f){0.f, 0.f, 0.f, 0.f};
    int arow = w * 16 + c;
    #pragma unroll
    for (int kc = 0; kc < 4; ++kc) {
        int ch = g + 4 * kc;
        v8bf aa = *(const v8bf*)&hc_s[arow][8 * (ch ^ (c & 7))];
        v8bf bb = *(const v8bf*)(W2B + c * 128 + ch * 8);
        acc2 = __builtin_amdgcn_mfma_f32_16x16x32_bf16(aa, bb, acc2, 0, 0, 0);
    }
    float b2c = b2[c];
    #pragma unroll
    for (int r = 0; r < 4; ++r) {
        int e = e_base + g * 4 + r;
        if (e < N_EDGES) out[(size_t)e * 16 + c] = acc2[r] + b2c;
    }
}

// ---------------------------------------------------------------------------
extern "C" void kernel_launch(void* const* d_in, const int* in_sizes, int n_in,
                              void* d_out, int out_size, void* d_ws, size_t ws_size,
                              hipStream_t stream) {
    const float* nf   = (const float*)d_in[0];
    const float* ef   = (const float*)d_in[1];
    const int*   ei   = (const int*)d_in[2];
    const int*   lab  = (const int*)d_in[3];
    const float* rel  = (const float*)d_in[4];
    const float* msgW = (const float*)d_in[5];
    const float* msgb = (const float*)d_in[6];
    const float* wih  = (const float*)d_in[7];
    const float* whh  = (const float*)d_in[8];
    const float* bih  = (const float*)d_in[9];
    const float* bhh  = (const float*)d_in[10];
    const float* W1   = (const float*)d_in[11];
    const float* b1   = (const float*)d_in[12];
    const float* W2   = (const float*)d_in[13];
    const float* b2   = (const float*)d_in[14];
    float* out = (float*)d_out;

    char* ws = (char*)d_ws;
    __bf16* WB      = (__bf16*)(ws);                  // 364.5 KB
    __bf16* RPB     = (__bf16*)(ws + 524288);         // 16 KB
    int*    offsets = (int*)(ws + 1048576);           // 200 KB (N+1)
    int*    counts  = (int*)(ws + 1310720);           // 200 KB
    int*    cursor  = (int*)(ws + 1572864);           // 200 KB
    int*    elist   = (int*)(ws + 1835008);           // 2 MB
    __bf16* PSTB    = (__bf16*)(ws + 4194304);        // 25.6 MB
    __bf16* AGG     = (__bf16*)(ws + 33554432);       // 12.8 MB
    __bf16* NFUB    = (__bf16*)(ws + 50331648);       // 12.8 MB
    __bf16* QSTB    = PSTB;                           // reuse after k_agg

    __bf16* WP1 = WB;
    __bf16* WQ1 = WB + 32768;
    __bf16* V3  = WB + 65536;
    __bf16* W2B = WB + 81920;
    __bf16* WIH = WB + 83968;
    __bf16* WHH = WB + 133120;

    int nblk = (N_NODES + 63) / 64;
    int eblk = (N_EDGES + 255) / 256;

    hipMemsetAsync(counts, 0, N_NODES * sizeof(int), stream);
    k_pre<<<744 + eblk, 256, 0, stream>>>(msgW, W1, W2, wih, whh, WB,
                                          rel, msgb, RPB, ei, counts);
    k_proj2_f32<<<nblk, 256, 0, stream>>>(nf, WP1, PSTB);
    k_scan<<<1, 256, 0, stream>>>(counts, offsets, cursor);
    k_scatter<<<eblk, 256, 0, stream>>>(ei, cursor, elist);
    k_agg<<<(N_NODES + 3) / 4, 256, 0, stream>>>(PSTB, RPB, ei, lab, offsets, elist, AGG);
    k_gru_mfma<<<nblk, 256, 0, stream>>>(AGG, nf, WIH, WHH, bih, bhh, NFUB);
    k_proj2_b16<<<nblk, 256, 0, stream>>>(NFUB, WQ1, QSTB);
    k_cls_mfma<<<(N_EDGES + 63) / 64, 256, 0, stream>>>(ef, QSTB, V3, b1, W2B, b2, ei, out);
}

// Round 12
// 515.166 us; speedup vs baseline: 1.2044x; 1.1468x over previous
//
#include <hip/hip_runtime.h>
#include <math.h>

#define N_NODES 50000
#define N_EDGES 500000
#define D 128
#define CAT 384

typedef __bf16 v8bf __attribute__((ext_vector_type(8)));
typedef __bf16 v2bf __attribute__((ext_vector_type(2)));
typedef float v4f __attribute__((ext_vector_type(4)));

// ---------------------------------------------------------------------------
// Fast transcendentals on the v_exp_f32 / v_rcp_f32 pipes.
__device__ __forceinline__ float erf_fast(float x) {
    float ax = fabsf(x);
    float t = __builtin_amdgcn_rcpf(fmaf(0.3275911f, ax, 1.0f));
    float p = fmaf(1.061405429f, t, -1.453152027f);
    p = fmaf(p, t, 1.421413741f);
    p = fmaf(p, t, -0.284496736f);
    p = fmaf(p, t, 0.254829592f);
    p = p * t;
    float e = __expf(-ax * ax);
    float r = 1.0f - p * e;
    return copysignf(r, x);
}

__device__ __forceinline__ float gelu_fast(float x) {
    return 0.5f * x * (1.0f + erf_fast(x * 0.70710678118654752440f));
}

__device__ __forceinline__ float sigmoid_fast(float x) {
    float e = __expf(-x);
    return __builtin_amdgcn_rcpf(1.0f + e);
}

__device__ __forceinline__ float tanh_fast(float x) {
    float e = __expf(2.0f * x);
    return 1.0f - 2.0f * __builtin_amdgcn_rcpf(e + 1.0f);
}

__device__ __forceinline__ v8bf cvt8(const float* __restrict__ p) {
    float4 f0 = *(const float4*)p;
    float4 f1 = *(const float4*)(p + 4);
    v8bf r;
    r[0] = (__bf16)f0.x; r[1] = (__bf16)f0.y; r[2] = (__bf16)f0.z; r[3] = (__bf16)f0.w;
    r[4] = (__bf16)f1.x; r[5] = (__bf16)f1.y; r[6] = (__bf16)f1.z; r[7] = (__bf16)f1.w;
    return r;
}

// ---------------------------------------------------------------------------
// Fused pre-pass: [0,712) weight cvt | [712,744) relpart | [744,...) histogram.
__global__ __launch_bounds__(256) void k_pre(const float* __restrict__ msgW,
                                             const float* __restrict__ W1,
                                             const float* __restrict__ W2,
                                             const float* __restrict__ wih,
                                             const float* __restrict__ whh,
                                             __bf16* __restrict__ WB,
                                             const float* __restrict__ rel_emb,
                                             const float* __restrict__ msg_b,
                                             __bf16* __restrict__ RPB,
                                             const int* __restrict__ ei,
                                             int* __restrict__ counts) {
    int bid = blockIdx.x;
    int t = threadIdx.x;
    if (bid < 712) {
        int i = bid * 256 + t;
        float v;
        if (i < 32768) {
            int j = i >> 7, k = i & 127;
            v = (j < 128) ? msgW[j * CAT + k] : msgW[(j - 128) * CAT + 128 + k];
        } else if (i < 65536) {
            int ii = i - 32768; int j = ii >> 7, k = ii & 127;
            v = (j < 128) ? W1[j * CAT + k] : W1[(j - 128) * CAT + 128 + k];
        } else if (i < 81920) {
            int ii = i - 65536; int j = ii >> 7, k = ii & 127;
            v = W1[j * CAT + 256 + k];
        } else if (i < 83968) {
            v = W2[i - 81920];
        } else if (i < 133120) {
            v = wih[i - 83968];
        } else {
            v = whh[i - 133120];
        }
        WB[i] = (__bf16)v;
    } else if (bid < 744) {
        int r = (bid - 712) * 2 + (t >> 7);
        int j = t & 127;
        const float* er = rel_emb + r * D;
        const float* wr = msgW + j * CAT + 2 * D;
        float acc = msg_b[j];
        #pragma unroll 8
        for (int k = 0; k < D; ++k) acc += er[k] * wr[k];
        RPB[r * D + j] = (__bf16)acc;
    } else {
        int e = (bid - 744) * 256 + t;
        if (e < N_EDGES) atomicAdd(&counts[ei[N_EDGES + e]], 1);
    }
}

// ---------------------------------------------------------------------------
// MFMA node projection (fp32 input), output-col remap j = half*128 + 8c + jt.
__global__ __launch_bounds__(256) void k_proj2_f32(const float* __restrict__ in,
                                                   const __bf16* __restrict__ wb,
                                                   __bf16* __restrict__ out) {
    int t = threadIdx.x;
    int lane = t & 63, wid = t >> 6;
    int g = lane >> 4, c = lane & 15;
    int nbase = blockIdx.x * 64 + wid * 16;

    int nrow = min(nbase + c, N_NODES - 1);
    const float* ir = in + (size_t)nrow * D + g * 8;
    v8bf afrag[4];
    #pragma unroll
    for (int kc = 0; kc < 4; ++kc) afrag[kc] = cvt8(ir + kc * 32);

    #pragma unroll
    for (int half = 0; half < 2; ++half) {
        v4f acc[8];
        #pragma unroll 2
        for (int jt = 0; jt < 8; ++jt) {
            const __bf16* wr = wb + (size_t)(half * 128 + 8 * c + jt) * 128 + g * 8;
            v4f a4 = (v4f){0.f, 0.f, 0.f, 0.f};
            #pragma unroll
            for (int kc = 0; kc < 4; ++kc)
                a4 = __builtin_amdgcn_mfma_f32_16x16x32_bf16(afrag[kc], *(const v8bf*)(wr + kc * 32), a4, 0, 0, 0);
            acc[jt] = a4;
        }
        #pragma unroll
        for (int r = 0; r < 4; ++r) {
            int node = nbase + g * 4 + r;
            v8bf o;
            #pragma unroll
            for (int jt = 0; jt < 8; ++jt) o[jt] = (__bf16)acc[jt][r];
            if (node < N_NODES)
                *(v8bf*)(out + (size_t)node * 256 + half * 128 + 8 * c) = o;
        }
    }
}

// bf16-input variant (for NFUB -> QSTB).
__global__ __launch_bounds__(256) void k_proj2_b16(const __bf16* __restrict__ in,
                                                   const __bf16* __restrict__ wb,
                                                   __bf16* __restrict__ out) {
    int t = threadIdx.x;
    int lane = t & 63, wid = t >> 6;
    int g = lane >> 4, c = lane & 15;
    int nbase = blockIdx.x * 64 + wid * 16;

    int nrow = min(nbase + c, N_NODES - 1);
    const __bf16* ir = in + (size_t)nrow * D + g * 8;
    v8bf afrag[4];
    #pragma unroll
    for (int kc = 0; kc < 4; ++kc) afrag[kc] = *(const v8bf*)(ir + kc * 32);

    #pragma unroll
    for (int half = 0; half < 2; ++half) {
        v4f acc[8];
        #pragma unroll 2
        for (int jt = 0; jt < 8; ++jt) {
            const __bf16* wr = wb + (size_t)(half * 128 + 8 * c + jt) * 128 + g * 8;
            v4f a4 = (v4f){0.f, 0.f, 0.f, 0.f};
            #pragma unroll
            for (int kc = 0; kc < 4; ++kc)
                a4 = __builtin_amdgcn_mfma_f32_16x16x32_bf16(afrag[kc], *(const v8bf*)(wr + kc * 32), a4, 0, 0, 0);
            acc[jt] = a4;
        }
        #pragma unroll
        for (int r = 0; r < 4; ++r) {
            int node = nbase + g * 4 + r;
            v8bf o;
            #pragma unroll
            for (int jt = 0; jt < 8; ++jt) o[jt] = (__bf16)acc[jt][r];
            if (node < N_NODES)
                *(v8bf*)(out + (size_t)node * 256 + half * 128 + 8 * c) = o;
        }
    }
}

// ---------------------------------------------------------------------------
// Single-block scan, 1024 threads (4x less serial latency than 256).
__global__ __launch_bounds__(1024) void k_scan(const int* __restrict__ counts,
                                               int* __restrict__ offsets,
                                               int* __restrict__ cursor) {
    __shared__ int part[1024];
    int t = threadIdx.x;
    const int CH = 49;                         // 1024*49 = 50176 >= 50000
    int lo = t * CH, hi = min(lo + CH, N_NODES);
    int s = 0;
    for (int i = lo; i < hi; ++i) s += counts[i];
    part[t] = s;
    __syncthreads();
    for (int d = 1; d < 1024; d <<= 1) {
        int v = (t >= d) ? part[t - d] : 0;
        __syncthreads();
        part[t] += v;
        __syncthreads();
    }
    int run = (t == 0) ? 0 : part[t - 1];
    for (int i = lo; i < hi; ++i) {
        offsets[i] = run;
        cursor[i] = run;
        run += counts[i];
    }
    if (t == 1023) offsets[N_NODES] = run;
}

__global__ __launch_bounds__(256) void k_scatter(const int* __restrict__ ei,
                                                 int* __restrict__ cursor,
                                                 int* __restrict__ elist) {
    int e = blockIdx.x * 256 + threadIdx.x;
    if (e < N_EDGES) {
        int slot = atomicAdd(&cursor[ei[N_EDGES + e]], 1);
        elist[slot] = e;
    }
}

// ---------------------------------------------------------------------------
// Aggregation, atomic-free; 4-deep index prefetch + 2-deep row-data prefetch
// (clamped lookahead: redundant loads instead of branches).
__global__ __launch_bounds__(256) void k_agg(const __bf16* __restrict__ PSTB,
                                             const __bf16* __restrict__ RPB,
                                             const int* __restrict__ ei,
                                             const int* __restrict__ lab,
                                             const int* __restrict__ offsets,
                                             const int* __restrict__ elist,
                                             __bf16* __restrict__ agg) {
    int t = threadIdx.x;
    int wid = t >> 6, lane = t & 63;
    int n = blockIdx.x * 4 + wid;
    if (n >= N_NODES) return;
    int beg = offsets[n], end = offsets[n + 1];

    v2bf ptv = *(const v2bf*)(PSTB + (size_t)n * 256 + 128 + lane * 2);
    float pt0 = (float)ptv[0], pt1 = (float)ptv[1];

    float a0 = 0.f, a1 = 0.f;
    if (beg < end) {
        int mx = end - 1;
        // indices for positions beg..beg+3 (clamped)
        int eA = elist[beg];
        int eB = elist[min(beg + 1, mx)];
        int e2 = elist[min(beg + 2, mx)];
        int e3 = elist[min(beg + 3, mx)];
        int sA = ei[eA], lA = lab[eA];
        int sB = ei[eB], lB = lab[eB];
        int s2 = ei[e2], l2 = lab[e2];
        int s3 = ei[e3], l3 = lab[e3];
        // data for positions beg, beg+1
        v2bf psA = *(const v2bf*)(PSTB + (size_t)sA * 256 + lane * 2);
        v2bf rpA = *(const v2bf*)(RPB + (size_t)lA * D + lane * 2);
        v2bf psB = *(const v2bf*)(PSTB + (size_t)sB * 256 + lane * 2);
        v2bf rpB = *(const v2bf*)(RPB + (size_t)lB * D + lane * 2);

        for (int idx = beg; idx < end; idx += 2) {
            v2bf cpsA = psA, crpA = rpA, cpsB = psB, crpB = rpB;
            bool hasB = (idx + 1 < end);
            // rotate data: load rows for idx+2, idx+3 (from s2/l2, s3/l3)
            psA = *(const v2bf*)(PSTB + (size_t)s2 * 256 + lane * 2);
            rpA = *(const v2bf*)(RPB + (size_t)l2 * D + lane * 2);
            psB = *(const v2bf*)(PSTB + (size_t)s3 * 256 + lane * 2);
            rpB = *(const v2bf*)(RPB + (size_t)l3 * D + lane * 2);
            // rotate indices: fetch idx+4, idx+5 (clamped)
            int e4 = elist[min(idx + 4, mx)];
            int e5 = elist[min(idx + 5, mx)];
            s2 = ei[e4]; l2 = lab[e4];
            s3 = ei[e5]; l3 = lab[e5];
            // consume
            a0 += gelu_fast((float)cpsA[0] + pt0 + (float)crpA[0]);
            a1 += gelu_fast((float)cpsA[1] + pt1 + (float)crpA[1]);
            if (hasB) {
                a0 += gelu_fast((float)cpsB[0] + pt0 + (float)crpB[0]);
                a1 += gelu_fast((float)cpsB[1] + pt1 + (float)crpB[1]);
            }
        }
    }
    v2bf o; o[0] = (__bf16)a0; o[1] = (__bf16)a1;
    *(v2bf*)(agg + (size_t)n * D + lane * 2) = o;
}

// ---------------------------------------------------------------------------
// MFMA GRU (unchanged structure, fast epilogue).
__global__ __launch_bounds__(256) void k_gru_mfma(const __bf16* __restrict__ agg,
                                                  const float* __restrict__ nf,
                                                  const __bf16* __restrict__ WIH,
                                                  const __bf16* __restrict__ WHH,
                                                  const float* __restrict__ b_ih,
                                                  const float* __restrict__ b_hh,
                                                  __bf16* __restrict__ nfu) {
    int t = threadIdx.x;
    int lane = t & 63, wid = t >> 6;
    int g = lane >> 4, c = lane & 15;
    int nbase = blockIdx.x * 64 + wid * 16;

    int nrow = min(nbase + c, N_NODES - 1);
    const __bf16* ar = agg + (size_t)nrow * D + g * 8;
    const float* hr = nf + (size_t)nrow * D + g * 8;
    v8bf afrag[4], hfrag[4];
    #pragma unroll
    for (int kc = 0; kc < 4; ++kc) {
        afrag[kc] = *(const v8bf*)(ar + kc * 32);
        hfrag[kc] = cvt8(hr + kc * 32);
    }

    float h8[4][8];
    #pragma unroll
    for (int r = 0; r < 4; ++r) {
        int node = min(nbase + g * 4 + r, N_NODES - 1);
        float4 f0 = *(const float4*)(nf + (size_t)node * D + 8 * c);
        float4 f1 = *(const float4*)(nf + (size_t)node * D + 8 * c + 4);
        h8[r][0]=f0.x; h8[r][1]=f0.y; h8[r][2]=f0.z; h8[r][3]=f0.w;
        h8[r][4]=f1.x; h8[r][5]=f1.y; h8[r][6]=f1.z; h8[r][7]=f1.w;
    }

    v8bf o[4];
    for (int jt = 0; jt < 8; ++jt) {
        int j = 8 * c + jt;
        const __bf16* wir = WIH + (size_t)j * 128 + g * 8;
        const __bf16* whr = WHH + (size_t)j * 128 + g * 8;
        v4f a_ir = (v4f){0.f,0.f,0.f,0.f}, a_iz = a_ir, a_in = a_ir;
        v4f a_hr = a_ir, a_hz = a_ir, a_hn = a_ir;
        #pragma unroll
        for (int kc = 0; kc < 4; ++kc) {
            a_ir = __builtin_amdgcn_mfma_f32_16x16x32_bf16(afrag[kc], *(const v8bf*)(wir + kc * 32), a_ir, 0, 0, 0);
            a_iz = __builtin_amdgcn_mfma_f32_16x16x32_bf16(afrag[kc], *(const v8bf*)(wir + 128 * 128 + kc * 32), a_iz, 0, 0, 0);
            a_in = __builtin_amdgcn_mfma_f32_16x16x32_bf16(afrag[kc], *(const v8bf*)(wir + 256 * 128 + kc * 32), a_in, 0, 0, 0);
            a_hr = __builtin_amdgcn_mfma_f32_16x16x32_bf16(hfrag[kc], *(const v8bf*)(whr + kc * 32), a_hr, 0, 0, 0);
            a_hz = __builtin_amdgcn_mfma_f32_16x16x32_bf16(hfrag[kc], *(const v8bf*)(whr + 128 * 128 + kc * 32), a_hz, 0, 0, 0);
            a_hn = __builtin_amdgcn_mfma_f32_16x16x32_bf16(hfrag[kc], *(const v8bf*)(whr + 256 * 128 + kc * 32), a_hn, 0, 0, 0);
        }
        float bir = b_ih[j], biz = b_ih[128 + j], bin = b_ih[256 + j];
        float bhr = b_hh[j], bhz = b_hh[128 + j], bhn = b_hh[256 + j];
        #pragma unroll
        for (int r = 0; r < 4; ++r) {
            float irv = a_ir[r] + bir, hrv = a_hr[r] + bhr;
            float izv = a_iz[r] + biz, hzv = a_hz[r] + bhz;
            float inv = a_in[r] + bin, hnv = a_hn[r] + bhn;
            float rg = sigmoid_fast(irv + hrv);
            float zg = sigmoid_fast(izv + hzv);
            float ng = tanh_fast(inv + rg * hnv);
            o[r][jt] = (__bf16)((1.f - zg) * ng + zg * h8[r][jt]);
        }
    }
    #pragma unroll
    for (int r = 0; r < 4; ++r) {
        int node = nbase + g * 4 + r;
        if (node < N_NODES) *(v8bf*)(nfu + (size_t)node * D + 8 * c) = o[r];
    }
}

// ---------------------------------------------------------------------------
// MFMA classifier v5: V3 staged in LDS (GEMM1 waits use lgkmcnt, never drain
// the QST gathers on vmcnt); ef issued before the single barrier so its HBM
// latency is absorbed by the barrier drain once per block. LDS 48KB.
// v3_s swizzle: chunk ch of row j stored at ch ^ ((j>>3)&7) — the row bits
// that vary across the 16 conflicting lanes (j = 8c+jt, j>>3 = c).
__global__ __launch_bounds__(256) void k_cls_mfma(const float* __restrict__ ef,
                                                  const __bf16* __restrict__ QSTB,
                                                  const __bf16* __restrict__ V3,
                                                  const float* __restrict__ b1,
                                                  const __bf16* __restrict__ W2B,
                                                  const float* __restrict__ b2,
                                                  const int* __restrict__ ei,
                                                  float* __restrict__ out) {
    __shared__ __align__(16) __bf16 v3_s[128][128];  // 32 KB
    __shared__ __align__(16) __bf16 hc_s[64][128];   // 16 KB
    int t = threadIdx.x;
    int lane = t & 63, w = t >> 6;
    int g = lane >> 4, c = lane & 15;
    int e0 = blockIdx.x * 64;
    int e_base = e0 + w * 16;

    // (1) ef HBM batch first — retires during the staging barrier
    int er = min(e_base + c, N_EDGES - 1);
    const float* efr = ef + (size_t)er * D + g * 8;
    float4 efraw[8];
    #pragma unroll
    for (int kc = 0; kc < 4; ++kc) {
        efraw[2 * kc]     = *(const float4*)(efr + kc * 32);
        efraw[2 * kc + 1] = *(const float4*)(efr + kc * 32 + 4);
    }

    // (2) edge indices (L2/L3, fast)
    int sr[4], tr[4];
    #pragma unroll
    for (int r = 0; r < 4; ++r) {
        int e = min(e_base + g * 4 + r, N_EDGES - 1);
        sr[r] = ei[e];
        tr[r] = ei[N_EDGES + e];
    }

    // (3) stage V3 into LDS, chunk-swizzled
    #pragma unroll
    for (int i = 0; i < 8; ++i) {
        int idx = t * 8 + i;            // 0..2047 16B-chunks
        int row = idx >> 4, ch = idx & 15;
        v8bf v = *(const v8bf*)(V3 + row * 128 + ch * 8);
        *(v8bf*)&v3_s[row][8 * (ch ^ ((row >> 3) & 7))] = v;
    }
    __syncthreads();   // drains ef + staging once per block

    // (4) QST gathers — issued now, consumed after GEMM1 (which is LDS-only)
    v8bf qsv[4], qtv[4];
    #pragma unroll
    for (int r = 0; r < 4; ++r) {
        qsv[r] = *(const v8bf*)(QSTB + (size_t)sr[r] * 256 + 8 * c);
        qtv[r] = *(const v8bf*)(QSTB + (size_t)tr[r] * 256 + 128 + 8 * c);
    }
    float4 b1a = *(const float4*)(b1 + 8 * c);
    float4 b1b = *(const float4*)(b1 + 8 * c + 4);
    float b1r[8] = {b1a.x, b1a.y, b1a.z, b1a.w, b1b.x, b1b.y, b1b.z, b1b.w};

    // (5) cvt ef -> A fragments (ef already retired)
    v8bf afrag[4];
    #pragma unroll
    for (int kc = 0; kc < 4; ++kc) {
        v8bf a;
        float4 f0 = efraw[2 * kc], f1 = efraw[2 * kc + 1];
        a[0] = (__bf16)f0.x; a[1] = (__bf16)f0.y; a[2] = (__bf16)f0.z; a[3] = (__bf16)f0.w;
        a[4] = (__bf16)f1.x; a[5] = (__bf16)f1.y; a[6] = (__bf16)f1.z; a[7] = (__bf16)f1.w;
        afrag[kc] = a;
    }

    // (6) GEMM1 from LDS — overlaps the in-flight gathers
    v4f acc[8];
    #pragma unroll
    for (int jt = 0; jt < 8; ++jt) {
        int row = 8 * c + jt;
        v4f a4 = (v4f){0.f, 0.f, 0.f, 0.f};
        #pragma unroll
        for (int kc = 0; kc < 4; ++kc) {
            v8bf bb = *(const v8bf*)&v3_s[row][8 * ((g + 4 * kc) ^ (c & 7))];
            a4 = __builtin_amdgcn_mfma_f32_16x16x32_bf16(afrag[kc], bb, a4, 0, 0, 0);
        }
        acc[jt] = a4;
    }

    // (7) epilogue: gathers + bias + gelu -> wave-local swizzled hc
    #pragma unroll
    for (int r = 0; r < 4; ++r) {
        int el = w * 16 + g * 4 + r;
        v8bf o;
        #pragma unroll
        for (int jt = 0; jt < 8; ++jt) {
            float v = acc[jt][r] + (float)qsv[r][jt] + (float)qtv[r][jt] + b1r[jt];
            o[jt] = (__bf16)gelu_fast(v);
        }
        *(v8bf*)&hc_s[el][8 * (c ^ (el & 7))] = o;
    }

    // (8) GEMM2: A from wave-local hc rows, B direct from W2B (L1-hot)
    v4f acc2 = (v4f){0.f, 0.f, 0.f, 0.f};
    int arow = w * 16 + c;
    #pragma unroll
    for (int kc = 0; kc < 4; ++kc) {
        int ch = g + 4 * kc;
        v8bf aa = *(const v8bf*)&hc_s[arow][8 * (ch ^ (c & 7))];
        v8bf bb = *(const v8bf*)(W2B + c * 128 + ch * 8);
        acc2 = __builtin_amdgcn_mfma_f32_16x16x32_bf16(aa, bb, acc2, 0, 0, 0);
    }
    float b2c = b2[c];
    #pragma unroll
    for (int r = 0; r < 4; ++r) {
        int e = e_base + g * 4 + r;
        if (e < N_EDGES) out[(size_t)e * 16 + c] = acc2[r] + b2c;
    }
}

// ---------------------------------------------------------------------------
extern "C" void kernel_launch(void* const* d_in, const int* in_sizes, int n_in,
                              void* d_out, int out_size, void* d_ws, size_t ws_size,
                              hipStream_t stream) {
    const float* nf   = (const float*)d_in[0];
    const float* ef   = (const float*)d_in[1];
    const int*   ei   = (const int*)d_in[2];
    const int*   lab  = (const int*)d_in[3];
    const float* rel  = (const float*)d_in[4];
    const float* msgW = (const float*)d_in[5];
    const float* msgb = (const float*)d_in[6];
    const float* wih  = (const float*)d_in[7];
    const float* whh  = (const float*)d_in[8];
    const float* bih  = (const float*)d_in[9];
    const float* bhh  = (const float*)d_in[10];
    const float* W1   = (const float*)d_in[11];
    const float* b1   = (const float*)d_in[12];
    const float* W2   = (const float*)d_in[13];
    const float* b2   = (const float*)d_in[14];
    float* out = (float*)d_out;

    char* ws = (char*)d_ws;
    __bf16* WB      = (__bf16*)(ws);                  // 364.5 KB
    __bf16* RPB     = (__bf16*)(ws + 524288);         // 16 KB
    int*    offsets = (int*)(ws + 1048576);           // 200 KB (N+1)
    int*    counts  = (int*)(ws + 1310720);           // 200 KB
    int*    cursor  = (int*)(ws + 1572864);           // 200 KB
    int*    elist   = (int*)(ws + 1835008);           // 2 MB
    __bf16* PSTB    = (__bf16*)(ws + 4194304);        // 25.6 MB
    __bf16* AGG     = (__bf16*)(ws + 33554432);       // 12.8 MB
    __bf16* NFUB    = (__bf16*)(ws + 50331648);       // 12.8 MB
    __bf16* QSTB    = PSTB;                           // reuse after k_agg

    __bf16* WP1 = WB;
    __bf16* WQ1 = WB + 32768;
    __bf16* V3  = WB + 65536;
    __bf16* W2B = WB + 81920;
    __bf16* WIH = WB + 83968;
    __bf16* WHH = WB + 133120;

    int nblk = (N_NODES + 63) / 64;
    int eblk = (N_EDGES + 255) / 256;

    hipMemsetAsync(counts, 0, N_NODES * sizeof(int), stream);
    k_pre<<<744 + eblk, 256, 0, stream>>>(msgW, W1, W2, wih, whh, WB,
                                          rel, msgb, RPB, ei, counts);
    k_proj2_f32<<<nblk, 256, 0, stream>>>(nf, WP1, PSTB);
    k_scan<<<1, 1024, 0, stream>>>(counts, offsets, cursor);
    k_scatter<<<eblk, 256, 0, stream>>>(ei, cursor, elist);
    k_agg<<<(N_NODES + 3) / 4, 256, 0, stream>>>(PSTB, RPB, ei, lab, offsets, elist, AGG);
    k_gru_mfma<<<nblk, 256, 0, stream>>>(AGG, nf, WIH, WHH, bih, bhh, NFUB);
    k_proj2_b16<<<nblk, 256, 0, stream>>>(NFUB, WQ1, QSTB);
    k_cls_mfma<<<(N_EDGES + 63) / 64, 256, 0, stream>>>(ef, QSTB, V3, b1, W2B, b2, ei, out);
}

// Round 13
// 511.138 us; speedup vs baseline: 1.2139x; 1.0079x over previous
//
#include <hip/hip_runtime.h>
#include <math.h>

#define N_NODES 50000
#define N_EDGES 500000
#define D 128
#define CAT 384

typedef __bf16 v8bf __attribute__((ext_vector_type(8)));
typedef __bf16 v2bf __attribute__((ext_vector_type(2)));
typedef float v4f __attribute__((ext_vector_type(4)));

// ---------------------------------------------------------------------------
// Fast transcendentals on the v_exp_f32 / v_rcp_f32 pipes.
__device__ __forceinline__ float erf_fast(float x) {
    float ax = fabsf(x);
    float t = __builtin_amdgcn_rcpf(fmaf(0.3275911f, ax, 1.0f));
    float p = fmaf(1.061405429f, t, -1.453152027f);
    p = fmaf(p, t, 1.421413741f);
    p = fmaf(p, t, -0.284496736f);
    p = fmaf(p, t, 0.254829592f);
    p = p * t;
    float e = __expf(-ax * ax);
    float r = 1.0f - p * e;
    return copysignf(r, x);
}

__device__ __forceinline__ float gelu_fast(float x) {
    return 0.5f * x * (1.0f + erf_fast(x * 0.70710678118654752440f));
}

__device__ __forceinline__ float sigmoid_fast(float x) {
    float e = __expf(-x);
    return __builtin_amdgcn_rcpf(1.0f + e);
}

__device__ __forceinline__ float tanh_fast(float x) {
    float e = __expf(2.0f * x);
    return 1.0f - 2.0f * __builtin_amdgcn_rcpf(e + 1.0f);
}

__device__ __forceinline__ v8bf cvt8(const float* __restrict__ p) {
    float4 f0 = *(const float4*)p;
    float4 f1 = *(const float4*)(p + 4);
    v8bf r;
    r[0] = (__bf16)f0.x; r[1] = (__bf16)f0.y; r[2] = (__bf16)f0.z; r[3] = (__bf16)f0.w;
    r[4] = (__bf16)f1.x; r[5] = (__bf16)f1.y; r[6] = (__bf16)f1.z; r[7] = (__bf16)f1.w;
    return r;
}

// ---------------------------------------------------------------------------
// Zero the counts array (replaces hipMemsetAsync -> rocclr fillBuffer, which
// cost ~150us in the captured graph).
__global__ __launch_bounds__(256) void k_zero(int* __restrict__ counts) {
    int i = blockIdx.x * 256 + threadIdx.x;
    if (i < N_NODES) counts[i] = 0;
}

// ---------------------------------------------------------------------------
// Fused pre-pass: [0,712) weight cvt | [712,744) relpart | [744,...) histogram.
__global__ __launch_bounds__(256) void k_pre(const float* __restrict__ msgW,
                                             const float* __restrict__ W1,
                                             const float* __restrict__ W2,
                                             const float* __restrict__ wih,
                                             const float* __restrict__ whh,
                                             __bf16* __restrict__ WB,
                                             const float* __restrict__ rel_emb,
                                             const float* __restrict__ msg_b,
                                             __bf16* __restrict__ RPB,
                                             const int* __restrict__ ei,
                                             int* __restrict__ counts) {
    int bid = blockIdx.x;
    int t = threadIdx.x;
    if (bid < 712) {
        int i = bid * 256 + t;
        float v;
        if (i < 32768) {
            int j = i >> 7, k = i & 127;
            v = (j < 128) ? msgW[j * CAT + k] : msgW[(j - 128) * CAT + 128 + k];
        } else if (i < 65536) {
            int ii = i - 32768; int j = ii >> 7, k = ii & 127;
            v = (j < 128) ? W1[j * CAT + k] : W1[(j - 128) * CAT + 128 + k];
        } else if (i < 81920) {
            int ii = i - 65536; int j = ii >> 7, k = ii & 127;
            v = W1[j * CAT + 256 + k];
        } else if (i < 83968) {
            v = W2[i - 81920];
        } else if (i < 133120) {
            v = wih[i - 83968];
        } else {
            v = whh[i - 133120];
        }
        WB[i] = (__bf16)v;
    } else if (bid < 744) {
        int r = (bid - 712) * 2 + (t >> 7);
        int j = t & 127;
        const float* er = rel_emb + r * D;
        const float* wr = msgW + j * CAT + 2 * D;
        float acc = msg_b[j];
        #pragma unroll 8
        for (int k = 0; k < D; ++k) acc += er[k] * wr[k];
        RPB[r * D + j] = (__bf16)acc;
    } else {
        int e = (bid - 744) * 256 + t;
        if (e < N_EDGES) atomicAdd(&counts[ei[N_EDGES + e]], 1);
    }
}

// ---------------------------------------------------------------------------
// MFMA node projection (fp32 input), output-col remap j = half*128 + 8c + jt.
__global__ __launch_bounds__(256) void k_proj2_f32(const float* __restrict__ in,
                                                   const __bf16* __restrict__ wb,
                                                   __bf16* __restrict__ out) {
    int t = threadIdx.x;
    int lane = t & 63, wid = t >> 6;
    int g = lane >> 4, c = lane & 15;
    int nbase = blockIdx.x * 64 + wid * 16;

    int nrow = min(nbase + c, N_NODES - 1);
    const float* ir = in + (size_t)nrow * D + g * 8;
    v8bf afrag[4];
    #pragma unroll
    for (int kc = 0; kc < 4; ++kc) afrag[kc] = cvt8(ir + kc * 32);

    #pragma unroll
    for (int half = 0; half < 2; ++half) {
        v4f acc[8];
        #pragma unroll 2
        for (int jt = 0; jt < 8; ++jt) {
            const __bf16* wr = wb + (size_t)(half * 128 + 8 * c + jt) * 128 + g * 8;
            v4f a4 = (v4f){0.f, 0.f, 0.f, 0.f};
            #pragma unroll
            for (int kc = 0; kc < 4; ++kc)
                a4 = __builtin_amdgcn_mfma_f32_16x16x32_bf16(afrag[kc], *(const v8bf*)(wr + kc * 32), a4, 0, 0, 0);
            acc[jt] = a4;
        }
        #pragma unroll
        for (int r = 0; r < 4; ++r) {
            int node = nbase + g * 4 + r;
            v8bf o;
            #pragma unroll
            for (int jt = 0; jt < 8; ++jt) o[jt] = (__bf16)acc[jt][r];
            if (node < N_NODES)
                *(v8bf*)(out + (size_t)node * 256 + half * 128 + 8 * c) = o;
        }
    }
}

// bf16-input variant (for NFUB -> QSTB).
__global__ __launch_bounds__(256) void k_proj2_b16(const __bf16* __restrict__ in,
                                                   const __bf16* __restrict__ wb,
                                                   __bf16* __restrict__ out) {
    int t = threadIdx.x;
    int lane = t & 63, wid = t >> 6;
    int g = lane >> 4, c = lane & 15;
    int nbase = blockIdx.x * 64 + wid * 16;

    int nrow = min(nbase + c, N_NODES - 1);
    const __bf16* ir = in + (size_t)nrow * D + g * 8;
    v8bf afrag[4];
    #pragma unroll
    for (int kc = 0; kc < 4; ++kc) afrag[kc] = *(const v8bf*)(ir + kc * 32);

    #pragma unroll
    for (int half = 0; half < 2; ++half) {
        v4f acc[8];
        #pragma unroll 2
        for (int jt = 0; jt < 8; ++jt) {
            const __bf16* wr = wb + (size_t)(half * 128 + 8 * c + jt) * 128 + g * 8;
            v4f a4 = (v4f){0.f, 0.f, 0.f, 0.f};
            #pragma unroll
            for (int kc = 0; kc < 4; ++kc)
                a4 = __builtin_amdgcn_mfma_f32_16x16x32_bf16(afrag[kc], *(const v8bf*)(wr + kc * 32), a4, 0, 0, 0);
            acc[jt] = a4;
        }
        #pragma unroll
        for (int r = 0; r < 4; ++r) {
            int node = nbase + g * 4 + r;
            v8bf o;
            #pragma unroll
            for (int jt = 0; jt < 8; ++jt) o[jt] = (__bf16)acc[jt][r];
            if (node < N_NODES)
                *(v8bf*)(out + (size_t)node * 256 + half * 128 + 8 * c) = o;
        }
    }
}

// ---------------------------------------------------------------------------
// Single-block scan, 1024 threads.
__global__ __launch_bounds__(1024) void k_scan(const int* __restrict__ counts,
                                               int* __restrict__ offsets,
                                               int* __restrict__ cursor) {
    __shared__ int part[1024];
    int t = threadIdx.x;
    const int CH = 49;                         // 1024*49 = 50176 >= 50000
    int lo = t * CH, hi = min(lo + CH, N_NODES);
    int s = 0;
    for (int i = lo; i < hi; ++i) s += counts[i];
    part[t] = s;
    __syncthreads();
    for (int d = 1; d < 1024; d <<= 1) {
        int v = (t >= d) ? part[t - d] : 0;
        __syncthreads();
        part[t] += v;
        __syncthreads();
    }
    int run = (t == 0) ? 0 : part[t - 1];
    for (int i = lo; i < hi; ++i) {
        offsets[i] = run;
        cursor[i] = run;
        run += counts[i];
    }
    if (t == 1023) offsets[N_NODES] = run;
}

__global__ __launch_bounds__(256) void k_scatter(const int* __restrict__ ei,
                                                 int* __restrict__ cursor,
                                                 int* __restrict__ elist) {
    int e = blockIdx.x * 256 + threadIdx.x;
    if (e < N_EDGES) {
        int slot = atomicAdd(&cursor[ei[N_EDGES + e]], 1);
        elist[slot] = e;
    }
}

// ---------------------------------------------------------------------------
// Aggregation, atomic-free; 4-deep index prefetch + 2-deep row-data prefetch.
__global__ __launch_bounds__(256) void k_agg(const __bf16* __restrict__ PSTB,
                                             const __bf16* __restrict__ RPB,
                                             const int* __restrict__ ei,
                                             const int* __restrict__ lab,
                                             const int* __restrict__ offsets,
                                             const int* __restrict__ elist,
                                             __bf16* __restrict__ agg) {
    int t = threadIdx.x;
    int wid = t >> 6, lane = t & 63;
    int n = blockIdx.x * 4 + wid;
    if (n >= N_NODES) return;
    int beg = offsets[n], end = offsets[n + 1];

    v2bf ptv = *(const v2bf*)(PSTB + (size_t)n * 256 + 128 + lane * 2);
    float pt0 = (float)ptv[0], pt1 = (float)ptv[1];

    float a0 = 0.f, a1 = 0.f;
    if (beg < end) {
        int mx = end - 1;
        int eA = elist[beg];
        int eB = elist[min(beg + 1, mx)];
        int e2 = elist[min(beg + 2, mx)];
        int e3 = elist[min(beg + 3, mx)];
        int sA = ei[eA], lA = lab[eA];
        int sB = ei[eB], lB = lab[eB];
        int s2 = ei[e2], l2 = lab[e2];
        int s3 = ei[e3], l3 = lab[e3];
        v2bf psA = *(const v2bf*)(PSTB + (size_t)sA * 256 + lane * 2);
        v2bf rpA = *(const v2bf*)(RPB + (size_t)lA * D + lane * 2);
        v2bf psB = *(const v2bf*)(PSTB + (size_t)sB * 256 + lane * 2);
        v2bf rpB = *(const v2bf*)(RPB + (size_t)lB * D + lane * 2);

        for (int idx = beg; idx < end; idx += 2) {
            v2bf cpsA = psA, crpA = rpA, cpsB = psB, crpB = rpB;
            bool hasB = (idx + 1 < end);
            psA = *(const v2bf*)(PSTB + (size_t)s2 * 256 + lane * 2);
            rpA = *(const v2bf*)(RPB + (size_t)l2 * D + lane * 2);
            psB = *(const v2bf*)(PSTB + (size_t)s3 * 256 + lane * 2);
            rpB = *(const v2bf*)(RPB + (size_t)l3 * D + lane * 2);
            int e4 = elist[min(idx + 4, mx)];
            int e5 = elist[min(idx + 5, mx)];
            s2 = ei[e4]; l2 = lab[e4];
            s3 = ei[e5]; l3 = lab[e5];
            a0 += gelu_fast((float)cpsA[0] + pt0 + (float)crpA[0]);
            a1 += gelu_fast((float)cpsA[1] + pt1 + (float)crpA[1]);
            if (hasB) {
                a0 += gelu_fast((float)cpsB[0] + pt0 + (float)crpB[0]);
                a1 += gelu_fast((float)cpsB[1] + pt1 + (float)crpB[1]);
            }
        }
    }
    v2bf o; o[0] = (__bf16)a0; o[1] = (__bf16)a1;
    *(v2bf*)(agg + (size_t)n * D + lane * 2) = o;
}

// ---------------------------------------------------------------------------
// MFMA GRU (unchanged structure, fast epilogue).
__global__ __launch_bounds__(256) void k_gru_mfma(const __bf16* __restrict__ agg,
                                                  const float* __restrict__ nf,
                                                  const __bf16* __restrict__ WIH,
                                                  const __bf16* __restrict__ WHH,
                                                  const float* __restrict__ b_ih,
                                                  const float* __restrict__ b_hh,
                                                  __bf16* __restrict__ nfu) {
    int t = threadIdx.x;
    int lane = t & 63, wid = t >> 6;
    int g = lane >> 4, c = lane & 15;
    int nbase = blockIdx.x * 64 + wid * 16;

    int nrow = min(nbase + c, N_NODES - 1);
    const __bf16* ar = agg + (size_t)nrow * D + g * 8;
    const float* hr = nf + (size_t)nrow * D + g * 8;
    v8bf afrag[4], hfrag[4];
    #pragma unroll
    for (int kc = 0; kc < 4; ++kc) {
        afrag[kc] = *(const v8bf*)(ar + kc * 32);
        hfrag[kc] = cvt8(hr + kc * 32);
    }

    float h8[4][8];
    #pragma unroll
    for (int r = 0; r < 4; ++r) {
        int node = min(nbase + g * 4 + r, N_NODES - 1);
        float4 f0 = *(const float4*)(nf + (size_t)node * D + 8 * c);
        float4 f1 = *(const float4*)(nf + (size_t)node * D + 8 * c + 4);
        h8[r][0]=f0.x; h8[r][1]=f0.y; h8[r][2]=f0.z; h8[r][3]=f0.w;
        h8[r][4]=f1.x; h8[r][5]=f1.y; h8[r][6]=f1.z; h8[r][7]=f1.w;
    }

    v8bf o[4];
    for (int jt = 0; jt < 8; ++jt) {
        int j = 8 * c + jt;
        const __bf16* wir = WIH + (size_t)j * 128 + g * 8;
        const __bf16* whr = WHH + (size_t)j * 128 + g * 8;
        v4f a_ir = (v4f){0.f,0.f,0.f,0.f}, a_iz = a_ir, a_in = a_ir;
        v4f a_hr = a_ir, a_hz = a_ir, a_hn = a_ir;
        #pragma unroll
        for (int kc = 0; kc < 4; ++kc) {
            a_ir = __builtin_amdgcn_mfma_f32_16x16x32_bf16(afrag[kc], *(const v8bf*)(wir + kc * 32), a_ir, 0, 0, 0);
            a_iz = __builtin_amdgcn_mfma_f32_16x16x32_bf16(afrag[kc], *(const v8bf*)(wir + 128 * 128 + kc * 32), a_iz, 0, 0, 0);
            a_in = __builtin_amdgcn_mfma_f32_16x16x32_bf16(afrag[kc], *(const v8bf*)(wir + 256 * 128 + kc * 32), a_in, 0, 0, 0);
            a_hr = __builtin_amdgcn_mfma_f32_16x16x32_bf16(hfrag[kc], *(const v8bf*)(whr + kc * 32), a_hr, 0, 0, 0);
            a_hz = __builtin_amdgcn_mfma_f32_16x16x32_bf16(hfrag[kc], *(const v8bf*)(whr + 128 * 128 + kc * 32), a_hz, 0, 0, 0);
            a_hn = __builtin_amdgcn_mfma_f32_16x16x32_bf16(hfrag[kc], *(const v8bf*)(whr + 256 * 128 + kc * 32), a_hn, 0, 0, 0);
        }
        float bir = b_ih[j], biz = b_ih[128 + j], bin = b_ih[256 + j];
        float bhr = b_hh[j], bhz = b_hh[128 + j], bhn = b_hh[256 + j];
        #pragma unroll
        for (int r = 0; r < 4; ++r) {
            float irv = a_ir[r] + bir, hrv = a_hr[r] + bhr;
            float izv = a_iz[r] + biz, hzv = a_hz[r] + bhz;
            float inv = a_in[r] + bin, hnv = a_hn[r] + bhn;
            float rg = sigmoid_fast(irv + hrv);
            float zg = sigmoid_fast(izv + hzv);
            float ng = tanh_fast(inv + rg * hnv);
            o[r][jt] = (__bf16)((1.f - zg) * ng + zg * h8[r][jt]);
        }
    }
    #pragma unroll
    for (int r = 0; r < 4; ++r) {
        int node = nbase + g * 4 + r;
        if (node < N_NODES) *(v8bf*)(nfu + (size_t)node * D + 8 * c) = o[r];
    }
}

// ---------------------------------------------------------------------------
// MFMA classifier v6: PERSISTENT blocks. V3 staged in LDS once per block
// (barrier once per block lifetime, not per tile); W2 fragments + biases
// hoisted to registers; 1-deep pipeline: gathers[t] issue at loop top
// (hidden under GEMM1), ef+idx[t+1] issue before GEMM1 (hidden under the
// whole loop body). hc round-trip stays wave-local (no in-loop barrier).
__global__ __launch_bounds__(256) void k_cls_mfma(const float* __restrict__ ef,
                                                  const __bf16* __restrict__ QSTB,
                                                  const __bf16* __restrict__ V3,
                                                  const float* __restrict__ b1,
                                                  const __bf16* __restrict__ W2B,
                                                  const float* __restrict__ b2,
                                                  const int* __restrict__ ei,
                                                  float* __restrict__ out) {
    __shared__ __align__(16) __bf16 v3_s[128][128];  // 32 KB
    __shared__ __align__(16) __bf16 hc_s[64][128];   // 16 KB
    int t = threadIdx.x;
    int lane = t & 63, w = t >> 6;
    int g = lane >> 4, c = lane & 15;
    const int ntile = (N_EDGES + 63) / 64;

    // prologue tile state
    int tile = blockIdx.x;
    int sr[4], tr[4];
    float4 efraw[8];
    if (tile < ntile) {
        int e_base = tile * 64 + w * 16;
        int er = min(e_base + c, N_EDGES - 1);
        const float* efr = ef + (size_t)er * D + g * 8;
        #pragma unroll
        for (int kc = 0; kc < 4; ++kc) {
            efraw[2 * kc]     = *(const float4*)(efr + kc * 32);
            efraw[2 * kc + 1] = *(const float4*)(efr + kc * 32 + 4);
        }
        #pragma unroll
        for (int r = 0; r < 4; ++r) {
            int e = min(e_base + g * 4 + r, N_EDGES - 1);
            sr[r] = ei[e];
            tr[r] = ei[N_EDGES + e];
        }
    }

    // hoisted invariants: W2 fragments, b1 row, b2
    v8bf w2frag[4];
    #pragma unroll
    for (int kc = 0; kc < 4; ++kc)
        w2frag[kc] = *(const v8bf*)(W2B + c * 128 + (g + 4 * kc) * 8);
    float4 b1a = *(const float4*)(b1 + 8 * c);
    float4 b1b = *(const float4*)(b1 + 8 * c + 4);
    float b1r[8] = {b1a.x, b1a.y, b1a.z, b1a.w, b1b.x, b1b.y, b1b.z, b1b.w};
    float b2c = b2[c];

    // stage V3 into LDS, chunk-swizzled (once per block)
    #pragma unroll
    for (int i = 0; i < 8; ++i) {
        int idx = t * 8 + i;
        int row = idx >> 4, ch = idx & 15;
        v8bf v = *(const v8bf*)(V3 + row * 128 + ch * 8);
        *(v8bf*)&v3_s[row][8 * (ch ^ ((row >> 3) & 7))] = v;
    }
    __syncthreads();

    while (tile < ntile) {
        int next = tile + gridDim.x;
        int e_base = tile * 64 + w * 16;

        // (a) gathers for CURRENT tile (indices arrived last iteration)
        v8bf qsv[4], qtv[4];
        #pragma unroll
        for (int r = 0; r < 4; ++r) {
            qsv[r] = *(const v8bf*)(QSTB + (size_t)sr[r] * 256 + 8 * c);
            qtv[r] = *(const v8bf*)(QSTB + (size_t)tr[r] * 256 + 128 + 8 * c);
        }

        // (b) cvt current ef -> A fragments (efraw arrived long ago)
        v8bf afrag[4];
        #pragma unroll
        for (int kc = 0; kc < 4; ++kc) {
            v8bf a;
            float4 f0 = efraw[2 * kc], f1 = efraw[2 * kc + 1];
            a[0] = (__bf16)f0.x; a[1] = (__bf16)f0.y; a[2] = (__bf16)f0.z; a[3] = (__bf16)f0.w;
            a[4] = (__bf16)f1.x; a[5] = (__bf16)f1.y; a[6] = (__bf16)f1.z; a[7] = (__bf16)f1.w;
            afrag[kc] = a;
        }

        // (c) issue NEXT tile ef + indices (consumed next iteration)
        int sr_n[4], tr_n[4];
        if (next < ntile) {
            int nb = next * 64 + w * 16;
            int er = min(nb + c, N_EDGES - 1);
            const float* efr = ef + (size_t)er * D + g * 8;
            #pragma unroll
            for (int kc = 0; kc < 4; ++kc) {
                efraw[2 * kc]     = *(const float4*)(efr + kc * 32);
                efraw[2 * kc + 1] = *(const float4*)(efr + kc * 32 + 4);
            }
            #pragma unroll
            for (int r = 0; r < 4; ++r) {
                int e = min(nb + g * 4 + r, N_EDGES - 1);
                sr_n[r] = ei[e];
                tr_n[r] = ei[N_EDGES + e];
            }
        }

        // (d) GEMM1 from LDS (lgkmcnt waits only; gathers stay in flight)
        v4f acc[8];
        #pragma unroll
        for (int jt = 0; jt < 8; ++jt) {
            int row = 8 * c + jt;
            v4f a4 = (v4f){0.f, 0.f, 0.f, 0.f};
            #pragma unroll
            for (int kc = 0; kc < 4; ++kc) {
                v8bf bb = *(const v8bf*)&v3_s[row][8 * ((g + 4 * kc) ^ (c & 7))];
                a4 = __builtin_amdgcn_mfma_f32_16x16x32_bf16(afrag[kc], bb, a4, 0, 0, 0);
            }
            acc[jt] = a4;
        }

        // (e) epilogue: gathers + bias + gelu -> wave-local swizzled hc
        #pragma unroll
        for (int r = 0; r < 4; ++r) {
            int el = w * 16 + g * 4 + r;
            v8bf o;
            #pragma unroll
            for (int jt = 0; jt < 8; ++jt) {
                float v = acc[jt][r] + (float)qsv[r][jt] + (float)qtv[r][jt] + b1r[jt];
                o[jt] = (__bf16)gelu_fast(v);
            }
            *(v8bf*)&hc_s[el][8 * (c ^ (el & 7))] = o;
        }

        // (f) GEMM2 + store
        v4f acc2 = (v4f){0.f, 0.f, 0.f, 0.f};
        int arow = w * 16 + c;
        #pragma unroll
        for (int kc = 0; kc < 4; ++kc) {
            int ch = g + 4 * kc;
            v8bf aa = *(const v8bf*)&hc_s[arow][8 * (ch ^ (c & 7))];
            acc2 = __builtin_amdgcn_mfma_f32_16x16x32_bf16(aa, w2frag[kc], acc2, 0, 0, 0);
        }
        #pragma unroll
        for (int r = 0; r < 4; ++r) {
            int e = e_base + g * 4 + r;
            if (e < N_EDGES) out[(size_t)e * 16 + c] = acc2[r] + b2c;
        }

        // rotate
        #pragma unroll
        for (int r = 0; r < 4; ++r) { sr[r] = sr_n[r]; tr[r] = tr_n[r]; }
        tile = next;
    }
}

// ---------------------------------------------------------------------------
extern "C" void kernel_launch(void* const* d_in, const int* in_sizes, int n_in,
                              void* d_out, int out_size, void* d_ws, size_t ws_size,
                              hipStream_t stream) {
    const float* nf   = (const float*)d_in[0];
    const float* ef   = (const float*)d_in[1];
    const int*   ei   = (const int*)d_in[2];
    const int*   lab  = (const int*)d_in[3];
    const float* rel  = (const float*)d_in[4];
    const float* msgW = (const float*)d_in[5];
    const float* msgb = (const float*)d_in[6];
    const float* wih  = (const float*)d_in[7];
    const float* whh  = (const float*)d_in[8];
    const float* bih  = (const float*)d_in[9];
    const float* bhh  = (const float*)d_in[10];
    const float* W1   = (const float*)d_in[11];
    const float* b1   = (const float*)d_in[12];
    const float* W2   = (const float*)d_in[13];
    const float* b2   = (const float*)d_in[14];
    float* out = (float*)d_out;

    char* ws = (char*)d_ws;
    __bf16* WB      = (__bf16*)(ws);                  // 364.5 KB
    __bf16* RPB     = (__bf16*)(ws + 524288);         // 16 KB
    int*    offsets = (int*)(ws + 1048576);           // 200 KB (N+1)
    int*    counts  = (int*)(ws + 1310720);           // 200 KB
    int*    cursor  = (int*)(ws + 1572864);           // 200 KB
    int*    elist   = (int*)(ws + 1835008);           // 2 MB
    __bf16* PSTB    = (__bf16*)(ws + 4194304);        // 25.6 MB
    __bf16* AGG     = (__bf16*)(ws + 33554432);       // 12.8 MB
    __bf16* NFUB    = (__bf16*)(ws + 50331648);       // 12.8 MB
    __bf16* QSTB    = PSTB;                           // reuse after k_agg

    __bf16* WP1 = WB;
    __bf16* WQ1 = WB + 32768;
    __bf16* V3  = WB + 65536;
    __bf16* W2B = WB + 81920;
    __bf16* WIH = WB + 83968;
    __bf16* WHH = WB + 133120;

    int nblk = (N_NODES + 63) / 64;
    int eblk = (N_EDGES + 255) / 256;

    k_zero<<<(N_NODES + 255) / 256, 256, 0, stream>>>(counts);
    k_pre<<<744 + eblk, 256, 0, stream>>>(msgW, W1, W2, wih, whh, WB,
                                          rel, msgb, RPB, ei, counts);
    k_proj2_f32<<<nblk, 256, 0, stream>>>(nf, WP1, PSTB);
    k_scan<<<1, 1024, 0, stream>>>(counts, offsets, cursor);
    k_scatter<<<eblk, 256, 0, stream>>>(ei, cursor, elist);
    k_agg<<<(N_NODES + 3) / 4, 256, 0, stream>>>(PSTB, RPB, ei, lab, offsets, elist, AGG);
    k_gru_mfma<<<nblk, 256, 0, stream>>>(AGG, nf, WIH, WHH, bih, bhh, NFUB);
    k_proj2_b16<<<nblk, 256, 0, stream>>>(NFUB, WQ1, QSTB);
    k_cls_mfma<<<768, 256, 0, stream>>>(ef, QSTB, V3, b1, W2B, b2, ei, out);
}